// Round 5
// baseline (240.558 us; speedup 1.0000x reference)
//
#include <hip/hip_runtime.h>
#include <math.h>

// DilatedAttention on MI355X (gfx950), bf16 MFMA implementation.
// L=4096, E=1024, H=16, D=64. Branches (sl,dr) = (1024,1),(2048,2),(4096,4).
// Every branch reduces to causal attention over g=1024 sparse positions.
//
// Attention in transposed-S form:
//   S^T = K Q^T  (lane l16 = q column)
//   O^T = V^T P^T with 16x16x16 MFMA    -> P^T registers are the B-operand.
// R4: XOR-swizzled LDS tiles via staging-source permutation.
// R5: q-tile PAIR (j, 15-j) per block: exactly 17 tile-computes each.
// exp2-domain softmax, defer-rescale, XCD-affinity attn remap.
// R6: fused dual-tile compute (shared K/V fragments, interleaved chains).
// R7: GEMM XCD-affinity remap; V^T pair-permuted (PV = 8x ds_read_b128,
// bank conflicts 2.7M -> 0 measured).
// R8: attn l-sum via ones-MFMA; setprio removed (measured regression).
// R9: fused fp32->bf16 A-conversion in gemm_qkv RESTRUCTURED: R8 put the
// cvt+ds_write between the two barriers (critical path; gemm 44->57us
// measured). Now lA is double-buffered: cvt+write of tile t+1 overlaps the
// MFMA phase of tile t (disjoint buffer, compiler interleaves into the MFMA
// stream); A-reg loads for t+2 issue in the same slot as B's
// global_load_lds and share its vmcnt drain. 2 barriers/iter, same as the
// measured-good m97 loop. cvt kernel stays weights-only.

#define L_SEQ 4096
#define EDIM  1024
#define NH    16
#define HD    64
#define GLEN  1024

typedef __bf16 bf16;
typedef __bf16 bf16x8 __attribute__((ext_vector_type(8)));
typedef __bf16 bf16x4 __attribute__((ext_vector_type(4)));
typedef short  s16x4  __attribute__((ext_vector_type(4)));
typedef float  f32x4  __attribute__((ext_vector_type(4)));

template <bool B> struct Flag { static constexpr bool v = B; };

// async global->LDS, 16B per lane. LDS dest semantics: wave-uniform base + lane*16.
__device__ __forceinline__ void gload16(const bf16* g, bf16* l) {
  __builtin_amdgcn_global_load_lds(
      (__attribute__((address_space(1))) void*)(const_cast<bf16*>(g)),
      (__attribute__((address_space(3))) void*)(l),
      16, 0, 0);
}

// v_mfma_f32_16x16x16_bf16 (builtin name only exists in the device pass).
__device__ __forceinline__ f32x4 mfma16x16x16_bf16(bf16x4 a, bf16x4 b, f32x4 c) {
#if defined(__HIP_DEVICE_COMPILE__)
  union { bf16x4 h; s16x4 s; } ua, ub;
  ua.h = a; ub.h = b;
  return __builtin_amdgcn_mfma_f32_16x16x16bf16_1k(ua.s, ub.s, c, 0, 0, 0);
#else
  (void)a; (void)b;
  return c;   // host stub, never executed
#endif
}

__device__ __forceinline__ float fast_exp2(float x) {
#if __has_builtin(__builtin_amdgcn_exp2f)
  return __builtin_amdgcn_exp2f(x);
#else
  return __expf(x * 0.6931471805599453f);
#endif
}

// ---------------------------------------------------------------------------
// fp32 -> bf16 conversion for Wq/Wk/Wv/Wo (E*E each). Q/K/V conversion is
// fused into gemm_qkv. Grid: (512, 4), exact cover.
// ---------------------------------------------------------------------------
__global__ __launch_bounds__(256) void cvt_kernel(
    const float* wq, const float* wk, const float* wv, const float* wo,
    bf16* owq, bf16* owk, bf16* owv, bf16* owo)
{
  const float* src; bf16* dst;
  switch (blockIdx.y) {
    case 0: src = wq; dst = owq; break;
    case 1: src = wk; dst = owk; break;
    case 2: src = wv; dst = owv; break;
    default: src = wo; dst = owo; break;
  }
  const int i = (blockIdx.x * 256 + threadIdx.x) * 8;
  const float4* s4 = (const float4*)(src + i);
  float4 a = s4[0], b = s4[1];
  bf16x8 o = { (bf16)a.x, (bf16)a.y, (bf16)a.z, (bf16)a.w,
               (bf16)b.x, (bf16)b.y, (bf16)b.z, (bf16)b.w };
  *(bf16x8*)(dst + i) = o;
}

// ---------------------------------------------------------------------------
// GEMM: C[m][n] = sum_k A[m][k] * W[n][k] + bias[n]   (B^T layout)
// M=4096, N=1024, K=1024. 128x128 tile, BK=32, 4 waves (2x2 of 64x64),
// 16x16x32 bf16 MFMA. B staged via global_load_lds. A: bf16 via
// global_load_lds (!AF32), or fp32 reg-staged with DOUBLE-BUFFERED lA --
// cvt+ds_write of tile t+1 overlaps MFMA of tile t (AF32).
// Grid MUST be (8, 32[, z]); XCD-affinity: HW XCD = flat%8 = blockIdx.x;
// XCD x owns row-panels [x*4, x*4+4).
// ---------------------------------------------------------------------------
template <typename OutT, bool AF32>
__device__ __forceinline__ void gemm_body(const void* __restrict__ Ap,
                                          const bf16* __restrict__ W,
                                          const float* __restrict__ bias,
                                          OutT* __restrict__ C)
{
  constexpr int K = 1024;
  __shared__ __align__(16) bf16 lA[2][128 * 32];
  __shared__ __align__(16) bf16 lB[128 * 32];

  const int tid  = threadIdx.x;
  const int lane = tid & 63;
  const int w    = tid >> 6;
  const int quad = lane >> 4;
  const int l16  = lane & 15;
  const int wr   = w >> 1, wc = w & 1;
  // XCD-affinity remap (bijective over 8x32): ly=x*4+(y>>3), lx=y&7
  const int ly = blockIdx.x * 4 + (blockIdx.y >> 3);
  const int lx = blockIdx.y & 7;
  const int row0 = ly * 128;
  const int col0 = lx * 128;

  f32x4 acc[4][4] = {};

  const int c0 = tid, c1 = tid + 256;
  const bf16* Bb0 = W + (size_t)(col0 + (c0 >> 2)) * K + (c0 & 3) * 8;
  const bf16* Bb1 = W + (size_t)(col0 + (c1 >> 2)) * K + (c1 & 3) * 8;

  if constexpr (AF32) {
    const float* Af = (const float*)Ap;
    const float* Af0 = Af + (size_t)(row0 + (c0 >> 2)) * K + (c0 & 3) * 8;
    const float* Af1 = Af + (size_t)(row0 + (c1 >> 2)) * K + (c1 & 3) * 8;
    float4 ar0, ar1, ar2, ar3;              // in-flight A regs (one tile)
    auto loadA = [&](int koff) {
      ar0 = *(const float4*)(Af0 + koff); ar1 = *(const float4*)(Af0 + koff + 4);
      ar2 = *(const float4*)(Af1 + koff); ar3 = *(const float4*)(Af1 + koff + 4);
    };
    auto writeA = [&](bf16* dst) {
      bf16x8 wa = { (bf16)ar0.x, (bf16)ar0.y, (bf16)ar0.z, (bf16)ar0.w,
                    (bf16)ar1.x, (bf16)ar1.y, (bf16)ar1.z, (bf16)ar1.w };
      bf16x8 wb = { (bf16)ar2.x, (bf16)ar2.y, (bf16)ar2.z, (bf16)ar2.w,
                    (bf16)ar3.x, (bf16)ar3.y, (bf16)ar3.z, (bf16)ar3.w };
      *(bf16x8*)&dst[c0 * 8] = wa;
      *(bf16x8*)&dst[c1 * 8] = wb;
    };

    // prologue: tile 0 direct to lA[0]; tile 1 loads in flight; B(0) staged
    loadA(0);
    writeA(&lA[0][0]);
    loadA(32);                              // issue tile 1 (drains at barrier)
    gload16(Bb0, &lB[c0 * 8]);
    gload16(Bb1, &lB[c1 * 8]);
    __syncthreads();                        // B(0)+A(1) arrived, lA[0] written

    for (int t = 0; t < 32; ++t) {
      const int cur = t & 1;
      bf16x8 af[4], bfrag[4];
#pragma unroll
      for (int mi = 0; mi < 4; mi++)
        af[mi] = *(const bf16x8*)&lA[cur][(wr * 64 + mi * 16 + l16) * 32 + quad * 8];
#pragma unroll
      for (int ni = 0; ni < 4; ni++)
        bfrag[ni] = *(const bf16x8*)&lB[(wc * 64 + ni * 16 + l16) * 32 + quad * 8];
      // cvt+write NEXT A tile into the other buffer: overlaps the MFMA phase
      if (t < 31) writeA(&lA[cur ^ 1][0]);
#pragma unroll
      for (int mi = 0; mi < 4; mi++)
#pragma unroll
        for (int ni = 0; ni < 4; ni++)
          acc[mi][ni] = __builtin_amdgcn_mfma_f32_16x16x32_bf16(
              af[mi], bfrag[ni], acc[mi][ni], 0, 0, 0);
      __syncthreads();                      // compute done (lB free), lA[nxt] written
      if (t < 31) {
        gload16(Bb0 + (t + 1) * 32, &lB[c0 * 8]);
        gload16(Bb1 + (t + 1) * 32, &lB[c1 * 8]);
        if (t < 30) loadA((t + 2) * 32);    // issue; shares B's vmcnt drain
        __syncthreads();                    // B(t+1) resident, A(t+2) arrived
      }
    }
  } else {
    const bf16* Ab = (const bf16*)Ap;
    const bf16* Ab0 = Ab + (size_t)(row0 + (c0 >> 2)) * K + (c0 & 3) * 8;
    const bf16* Ab1 = Ab + (size_t)(row0 + (c1 >> 2)) * K + (c1 & 3) * 8;
    for (int kt = 0; kt < K; kt += 32) {
      __syncthreads();
      gload16(Ab0 + kt, &lA[0][c0 * 8]);
      gload16(Ab1 + kt, &lA[0][c1 * 8]);
      gload16(Bb0 + kt, &lB[c0 * 8]);
      gload16(Bb1 + kt, &lB[c1 * 8]);
      __syncthreads();

      bf16x8 af[4], bfrag[4];
#pragma unroll
      for (int mi = 0; mi < 4; mi++)
        af[mi] = *(const bf16x8*)&lA[0][(wr * 64 + mi * 16 + l16) * 32 + quad * 8];
#pragma unroll
      for (int ni = 0; ni < 4; ni++)
        bfrag[ni] = *(const bf16x8*)&lB[(wc * 64 + ni * 16 + l16) * 32 + quad * 8];
#pragma unroll
      for (int mi = 0; mi < 4; mi++)
#pragma unroll
        for (int ni = 0; ni < 4; ni++)
          acc[mi][ni] = __builtin_amdgcn_mfma_f32_16x16x32_bf16(
              af[mi], bfrag[ni], acc[mi][ni], 0, 0, 0);
    }
  }

#pragma unroll
  for (int mi = 0; mi < 4; mi++) {
#pragma unroll
    for (int ni = 0; ni < 4; ni++) {
      const int gcol = col0 + wc * 64 + ni * 16 + l16;
      const float bv = bias[gcol];
#pragma unroll
      for (int r = 0; r < 4; r++) {
        const int grow = row0 + wr * 64 + mi * 16 + quad * 4 + r;
        C[(size_t)grow * 1024 + gcol] = (OutT)(acc[mi][ni][r] + bv);
      }
    }
  }
}

__global__ __launch_bounds__(256) void gemm_qkv_kernel(
    const float* q, const float* k, const float* v,
    const bf16* wq, const bf16* wk, const bf16* wv,
    const float* bq, const float* bk, const float* bv,
    bf16* qo, bf16* ko, bf16* vo)
{
  const float *A, *bias; const bf16* W; bf16* C;
  if (blockIdx.z == 0)      { A = q; W = wq; bias = bq; C = qo; }
  else if (blockIdx.z == 1) { A = k; W = wk; bias = bk; C = ko; }
  else                      { A = v; W = wv; bias = bv; C = vo; }
  gemm_body<bf16, true>(A, W, bias, C);
}

__global__ __launch_bounds__(256) void gemm_out_kernel(
    const bf16* A, const bf16* W, const float* bias, float* C)
{
  gemm_body<float, false>(A, W, bias, C);
}

// ---------------------------------------------------------------------------
// V transpose into per-branch sparse-contiguous layout: vt_b[seg][h][d][kj'].
// kj' is PAIR-PERMUTED within each 64-kpos tile-row: chunk c' = p2*4 + q
// (p2 in {0,1}, q in {0..3}) holds old kpos {p2*32+q*4..+4} ++
// {p2*32+16+q*4..+4}, so one 16B read serves MFMA pair (t=2p2, 2p2+1).
// ---------------------------------------------------------------------------
__global__ __launch_bounds__(256) void vtrans_kernel(
    const bf16* __restrict__ v, bf16* vt0, bf16* vt1, bf16* vt2)
{
  __shared__ __align__(16) bf16 ltile[64 * 72];   // [kj][d], padded
  const int bid = blockIdx.x;
  int sl, dr, rem, shift; bf16* vt;
  if (bid < 1024)      { sl = 1024; dr = 1; rem = bid;        vt = vt0; shift = 4; }
  else if (bid < 1536) { sl = 2048; dr = 2; rem = bid - 1024; vt = vt1; shift = 3; }
  else                 { sl = 4096; dr = 4; rem = bid - 1536; vt = vt2; shift = 2; }
  const int ktile = rem & 15;
  const int h     = (rem >> 4) & 15;
  const int seg   = rem >> 8;
  const int grp   = h >> shift;          // h / (16/dr)
  const int segbase = seg * sl;
  const int tid = threadIdx.x;
  {
    const int i = tid >> 2, dc = tid & 3;
    const size_t p = (size_t)(segbase + (ktile * 64 + i) * dr + grp);
    const bf16* src = v + p * EDIM + h * 64 + dc * 16;
    *(uint4*)&ltile[i * 72 + dc * 16]     = *(const uint4*)(src);
    *(uint4*)&ltile[i * 72 + dc * 16 + 8] = *(const uint4*)(src + 8);
  }
  __syncthreads();
  {
    const int d = tid >> 2, kc = tid & 3;   // kc = t (old 16-kpos group)
    __align__(16) bf16 tmp[16];
#pragma unroll
    for (int j = 0; j < 16; j++) tmp[j] = ltile[(kc * 16 + j) * 72 + d];
    // pair-permuted destination: newpos = p2*32 + q*8 + half*4 + r
    const int p2 = kc >> 1, half = kc & 1;
    bf16* dst = vt + ((size_t)(seg * NH + h) * 64 + d) * GLEN + ktile * 64
                   + p2 * 32 + half * 4;
#pragma unroll
    for (int q = 0; q < 4; q++) {
      bf16x4 piece = { tmp[q * 4 + 0], tmp[q * 4 + 1],
                       tmp[q * 4 + 2], tmp[q * 4 + 3] };
      *(bf16x4*)(dst + q * 8) = piece;
    }
  }
}

// ---------------------------------------------------------------------------
// Flash attention, transposed-S form with XOR-swizzled LDS tiles.
// Block = (branch, seg, h, pair j): q-tiles qtA = 15-j and qtB = j over one
// shared staged K/V stream. Dual-tile fused compute: both tiles consume the
// SAME K/V fragments, softmax chains interleave. l-sum via ones-MFMA.
// ---------------------------------------------------------------------------
__global__ __launch_bounds__(256, 4) void attn_kernel(
    const bf16* __restrict__ qg, const bf16* __restrict__ kg,
    const bf16* vt0, const bf16* vt1, const bf16* vt2,
    bf16* o0, bf16* o1, bf16* o2,
    float* l0, float* l1, float* l2)
{
  __shared__ __align__(16) bf16 lK[2][64 * 64];     // [kj][d], swizzled
  __shared__ __align__(16) bf16 lV[2][64 * 64];     // [d][kj'], swizzled

  // XCD-affinity remap (bijective, 896 = 8*112): hardware assigns block b to
  // XCD b%8; logical id o = (b&7)*112 + (b>>3) gives each XCD a contiguous
  // run of 112 logical blocks = 14 (seg,h) groups -> K/V fits that XCD's L2.
  const int bid0 = blockIdx.x;
  const int o = (bid0 & 7) * 112 + (bid0 >> 3);

  int sl, dr, rem, shift;
  const bf16* vt; bf16* ob; float* lseb;
  if (o < 512)      { sl = 1024; dr = 1; rem = o;       vt = vt0; ob = o0; lseb = l0; shift = 4; }
  else if (o < 768) { sl = 2048; dr = 2; rem = o - 512; vt = vt1; ob = o1; lseb = l1; shift = 3; }
  else              { sl = 4096; dr = 4; rem = o - 768; vt = vt2; ob = o2; lseb = l2; shift = 2; }
  const int j   = rem & 7;
  const int h   = (rem >> 3) & 15;
  const int seg = rem >> 7;
  const int qtA = 15 - j;                // high q-tile (16-j k-iterations)
  const int qtB = j;                     // low q-tile  (j+1 k-iterations); qtB < qtA
  const int grp = h >> shift;
  const int segbase = seg * sl;

  const int tid = threadIdx.x, lane = tid & 63, w = tid >> 6;
  const int quad = lane >> 4, l16 = lane & 15;
  const int rs8 = l16 & 7;               // row-XOR term: (kj&7)==(drow&7)==l16&7

  // Q fragments (B-operand of S^T MFMA): B[k=d=quad*8+j][n=q=l16]
  auto loadq = [&](int qt, bf16x8& a0, bf16x8& a1) {
    const int qi = qt * 64 + w * 16 + l16;
    const size_t p = (size_t)(segbase + qi * dr + grp);
    const bf16* qp = qg + p * EDIM + h * 64 + quad * 8;
    a0 = *(const bf16x8*)(qp);
    a1 = *(const bf16x8*)(qp + 32);
  };
  bf16x8 qaA0, qaA1, qaB0, qaB1;
  loadq(qtA, qaA0, qaA1);
  loadq(qtB, qaB0, qaB1);

  f32x4 OA[4] = {}, OB[4] = {};          // O^T frags: col l16=q, row = d
  f32x4 lsA = {0.f, 0.f, 0.f, 0.f};      // l accumulated by ones-MFMA
  f32x4 lsB = {0.f, 0.f, 0.f, 0.f};
  float mA = -__builtin_inff();          // m in log2 units
  float mB = -__builtin_inff();
  const bf16x4 ONES = { (bf16)1.f, (bf16)1.f, (bf16)1.f, (bf16)1.f };

  const bf16* vbase = vt + (size_t)(seg * NH + h) * 64 * GLEN;
  const int c0 = tid, c1 = tid + 256;
  // staging-source permutation implementing the XOR swizzle:
  // LDS chunk position p (=c0/c1) is row r=p>>3, slot s=p&7; it must receive
  // global chunk c = s ^ (r & 7).
  const int r0 = c0 >> 3, sw0 = ((c0 & 7) ^ (r0 & 7));
  const int r1 = c1 >> 3, sw1 = ((c1 & 7) ^ (r1 & 7));

  // incremental staging pointers (advance one k-tile per stage call)
  const bf16* kp0 = kg + (size_t)(segbase + r0 * dr + grp) * EDIM + h * 64 + sw0 * 8;
  const bf16* kp1 = kg + (size_t)(segbase + r1 * dr + grp) * EDIM + h * 64 + sw1 * 8;
  const bf16* vp0 = vbase + (size_t)r0 * GLEN + sw0 * 8;
  const bf16* vp1 = vbase + (size_t)r1 * GLEN + sw1 * 8;
  const size_t kstep = (size_t)64 * dr * EDIM;

  auto stage = [&](int buf) {
    gload16(kp0, &lK[buf][c0 * 8]);
    gload16(kp1, &lK[buf][c1 * 8]);
    gload16(vp0, &lV[buf][c0 * 8]);
    gload16(vp1, &lV[buf][c1 * 8]);
    kp0 += kstep; kp1 += kstep; vp0 += 64; vp1 += 64;
  };

  const float CS = 0.18033688011112042f;   // (1/sqrt(64)) * log2(e)
  const float NEGINF = -__builtin_inff();
  const int qiA = qtA * 64 + w * 16 + l16;
  const int qiB = qtB * 64 + w * 16 + l16;

  // loop-invariant LDS read bases (K: kj = t*16+l16 -> +t*1024; V: +nf*1024)
  const int kb0 = l16 * 64 + ((quad ^ rs8) * 8);
  const int kb1 = l16 * 64 + (((4 + quad) ^ rs8) * 8);
  const int vb0 = l16 * 64;

  // Fused dual-tile compute. HAS_B: tile B active this k-tile. DIAG_A/B:
  // causal-diagonal masking for that tile (DIAG_A implies !HAS_B).
  auto comp = [&](auto hasB_, auto diagA_, auto diagB_, int kt) {
    constexpr bool HAS_B  = decltype(hasB_)::v;
    constexpr bool DIAG_A = decltype(diagA_)::v;
    constexpr bool DIAG_B = decltype(diagB_)::v;
    const bf16* bK = lK[kt & 1];
    const bf16* bV = lV[kt & 1];

    // --- S^T = K Q^T for both tiles off shared K fragments ---
    f32x4 sA[4], sB[4];
#pragma unroll
    for (int t = 0; t < 4; t++) {
      const bool aA = !DIAG_A || t <= w;
      const bool aB = HAS_B && (!DIAG_B || t <= w);
      if (aA || aB) {
        bf16x8 ka0 = *(const bf16x8*)&bK[kb0 + t * 1024];
        bf16x8 ka1 = *(const bf16x8*)&bK[kb1 + t * 1024];
        if (aA) {
          sA[t] = f32x4{0.f, 0.f, 0.f, 0.f};
          sA[t] = __builtin_amdgcn_mfma_f32_16x16x32_bf16(ka0, qaA0, sA[t], 0, 0, 0);
          sA[t] = __builtin_amdgcn_mfma_f32_16x16x32_bf16(ka1, qaA1, sA[t], 0, 0, 0);
        }
        if (aB) {
          sB[t] = f32x4{0.f, 0.f, 0.f, 0.f};
          sB[t] = __builtin_amdgcn_mfma_f32_16x16x32_bf16(ka0, qaB0, sB[t], 0, 0, 0);
          sB[t] = __builtin_amdgcn_mfma_f32_16x16x32_bf16(ka1, qaB1, sB[t], 0, 0, 0);
        }
      }
    }

    // --- masked raw max, vector partials ---
    f32x4 mvA = {NEGINF, NEGINF, NEGINF, NEGINF};
    f32x4 mvB = {NEGINF, NEGINF, NEGINF, NEGINF};
#pragma unroll
    for (int t = 0; t < 4; t++) {
      if (!DIAG_A || t <= w) {
#pragma unroll
        for (int r = 0; r < 4; r++) {
          float sv = sA[t][r];
          if (DIAG_A) {
            const int kj = kt * 64 + t * 16 + quad * 4 + r;
            if (kj > qiA) sv = NEGINF;
          }
          sA[t][r] = sv;
          mvA[r] = fmaxf(mvA[r], sv);
        }
      }
      if (HAS_B && (!DIAG_B || t <= w)) {
#pragma unroll
        for (int r = 0; r < 4; r++) {
          float sv = sB[t][r];
          if (DIAG_B) {
            const int kj = kt * 64 + t * 16 + quad * 4 + r;
            if (kj > qiB) sv = NEGINF;
          }
          sB[t][r] = sv;
          mvB[r] = fmaxf(mvB[r], sv);
        }
      }
    }
    float mrA = fmaxf(fmaxf(mvA[0], mvA[1]), fmaxf(mvA[2], mvA[3]));
    float mrB = fmaxf(fmaxf(mvB[0], mvB[1]), fmaxf(mvB[2], mvB[3]));
    mrA = fmaxf(mrA, __shfl_xor(mrA, 16, 64));
    mrA = fmaxf(mrA, __shfl_xor(mrA, 32, 64));
    if constexpr (HAS_B) {
      mrB = fmaxf(mrB, __shfl_xor(mrB, 16, 64));
      mrB = fmaxf(mrB, __shfl_xor(mrB, 32, 64));
    }

    // --- defer-rescale (T13), wave-uniform skip ---
    {
      const float mnew = fmaxf(mA, mrA * CS);
      if (!__all(mnew - mA <= 8.0f)) {
        const float alpha = fast_exp2(mA - mnew);   // first tile: exp2(-inf)=0
#pragma unroll
        for (int nf = 0; nf < 4; nf++)
#pragma unroll
          for (int r = 0; r < 4; r++) OA[nf][r] *= alpha;
#pragma unroll
        for (int r = 0; r < 4; r++) lsA[r] *= alpha;
        mA = mnew;
      }
    }
    if constexpr (HAS_B) {
      const float mnew = fmaxf(mB, mrB * CS);
      if (!__all(mnew - mB <= 8.0f)) {
        const float alpha = fast_exp2(mB - mnew);
#pragma unroll
        for (int nf = 0; nf < 4; nf++)
#pragma unroll
          for (int r = 0; r < 4; r++) OB[nf][r] *= alpha;
#pragma unroll
        for (int r = 0; r < 4; r++) lsB[r] *= alpha;
        mB = mnew;
      }
    }

    // --- p = exp2(fma(s_raw, CS, -m)) <= 2^8; bf16 pack ---
    bf16x4 pbA[4], pbB[4];
#pragma unroll
    for (int t = 0; t < 4; t++) {
      if (!DIAG_A || t <= w) {
#pragma unroll
        for (int r = 0; r < 4; r++)
          pbA[t][r] = (bf16)fast_exp2(__builtin_fmaf(sA[t][r], CS, -mA));
      }
      if (HAS_B && (!DIAG_B || t <= w)) {
#pragma unroll
        for (int r = 0; r < 4; r++)
          pbB[t][r] = (bf16)fast_exp2(__builtin_fmaf(sB[t][r], CS, -mB));
      }
    }

    // --- O^T += V^T P^T off shared V fragments (paired b128 reads);
    //     l += ones-MFMA(P^T): full 64-kpos row sum incl. cross-quad ---
#pragma unroll
    for (int p2 = 0; p2 < 2; p2++) {
      const int t0 = 2 * p2, t1 = t0 + 1;
      const bool aA0 = !DIAG_A || t0 <= w;
      const bool aA1 = !DIAG_A || t1 <= w;
      const bool aB0 = HAS_B && (!DIAG_B || t0 <= w);
      const bool aB1 = HAS_B && (!DIAG_B || t1 <= w);
      if (aA0 || aA1 || aB0 || aB1) {
        const int cx = ((p2 * 4 + quad) ^ rs8) * 8;
#pragma unroll
        for (int nf = 0; nf < 4; nf++) {
          bf16x8 va8 = *(const bf16x8*)&bV[vb0 + nf * 1024 + cx];
          bf16x4 vlo = __builtin_shufflevector(va8, va8, 0, 1, 2, 3);
          bf16x4 vhi = __builtin_shufflevector(va8, va8, 4, 5, 6, 7);
          if (aA0) OA[nf] = mfma16x16x16_bf16(vlo, pbA[t0], OA[nf]);
          if (aA1) OA[nf] = mfma16x16x16_bf16(vhi, pbA[t1], OA[nf]);
          if (aB0) OB[nf] = mfma16x16x16_bf16(vlo, pbB[t0], OB[nf]);
          if (aB1) OB[nf] = mfma16x16x16_bf16(vhi, pbB[t1], OB[nf]);
        }
        if (aA0) lsA = mfma16x16x16_bf16(ONES, pbA[t0], lsA);
        if (aA1) lsA = mfma16x16x16_bf16(ONES, pbA[t1], lsA);
        if (aB0) lsB = mfma16x16x16_bf16(ONES, pbB[t0], lsB);
        if (aB1) lsB = mfma16x16x16_bf16(ONES, pbB[t1], lsB);
      }
    }
  };

  stage(0);
  int kt = 0;
  // Phase 1: both tiles, no diagonal (kt < qtB)
  for (; kt < qtB; kt++) {
    __syncthreads();
    stage((kt + 1) & 1);
    comp(Flag<true>{}, Flag<false>{}, Flag<false>{}, kt);
  }
  // kt == qtB: tile A full, tile B diagonal (qtB < qtA always)
  __syncthreads();
  stage((kt + 1) & 1);
  comp(Flag<true>{}, Flag<false>{}, Flag<true>{}, kt);
  kt++;
  // Phase 2: tile A only (qtB < kt < qtA)
  for (; kt < qtA; kt++) {
    __syncthreads();
    stage((kt + 1) & 1);
    comp(Flag<false>{}, Flag<false>{}, Flag<false>{}, kt);
  }
  // kt == qtA: tile A diagonal
  __syncthreads();
  comp(Flag<false>{}, Flag<true>{}, Flag<false>{}, kt);

  // epilogue: lane l16 owns q column; d = nf*16 + quad*4 + r (4 contiguous)
  auto epilogue = [&](const f32x4 (&Oa)[4], float m_r, float l_r, int qt) {
    const int qi = qt * 64 + w * 16 + l16;
    const float linv = 1.0f / l_r;
    const int pdense = segbase + qi * dr + grp;
    bf16* orow = ob + (size_t)pdense * EDIM + h * 64;
#pragma unroll
    for (int nf = 0; nf < 4; nf++) {
      bf16x4 ov;
#pragma unroll
      for (int r = 0; r < 4; r++) ov[r] = (bf16)(Oa[nf][r] * linv);
      *(bf16x4*)(orow + nf * 16 + quad * 4) = ov;
    }
    if (quad == 0)
      lseb[h * L_SEQ + pdense] = m_r * 0.6931471805599453f + __logf(l_r);
  };
  epilogue(OA, mA, lsA[0], qtA);
  epilogue(OB, mB, lsB[0], qtB);
}

// ---------------------------------------------------------------------------
// Merge: softmax over branch lse at each (h,p); coverage computed analytically.
// ---------------------------------------------------------------------------
__global__ __launch_bounds__(256) void merge_kernel(
    const bf16* __restrict__ o0, const bf16* __restrict__ o1, const bf16* __restrict__ o2,
    const float* __restrict__ l0, const float* __restrict__ l1, const float* __restrict__ l2,
    bf16* __restrict__ merged)
{
  const int idx = blockIdx.x * 256 + threadIdx.x;   // over L*H*8
  const int dc = idx & 7;
  const int h  = (idx >> 3) & 15;
  const int p  = idx >> 7;
  const bool c1 = ((p & 1) == (h >> 3));   // branch dr=2 coverage
  const bool c2 = ((p & 3) == (h >> 2));   // branch dr=4 coverage
  const float s0 = l0[h * L_SEQ + p];
  const float s1 = c1 ? l1[h * L_SEQ + p] : -__builtin_inff();
  const float s2 = c2 ? l2[h * L_SEQ + p] : -__builtin_inff();
  const float mx = fmaxf(s0, fmaxf(s1, s2));
  float w0 = __expf(s0 - mx);
  float w1 = c1 ? __expf(s1 - mx) : 0.f;
  float w2 = c2 ? __expf(s2 - mx) : 0.f;
  const float inv = 1.0f / (w0 + w1 + w2);
  w0 *= inv; w1 *= inv; w2 *= inv;

  const size_t off = (size_t)p * EDIM + h * 64 + dc * 8;
  float acc[8];
  bf16x8 a0 = *(const bf16x8*)(o0 + off);
#pragma unroll
  for (int j = 0; j < 8; j++) acc[j] = w0 * (float)a0[j];
  if (c1) {
    bf16x8 a1 = *(const bf16x8*)(o1 + off);
#pragma unroll
    for (int j = 0; j < 8; j++) acc[j] += w1 * (float)a1[j];
  }
  if (c2) {
    bf16x8 a2 = *(const bf16x8*)(o2 + off);
#pragma unroll
    for (int j = 0; j < 8; j++) acc[j] += w2 * (float)a2[j];
  }
  bf16x8 r;
#pragma unroll
  for (int j = 0; j < 8; j++) r[j] = (bf16)acc[j];
  *(bf16x8*)(merged + off) = r;
}

// ---------------------------------------------------------------------------
extern "C" void kernel_launch(void* const* d_in, const int* in_sizes, int n_in,
                              void* d_out, int out_size, void* d_ws, size_t ws_size,
                              hipStream_t stream)
{
  (void)in_sizes; (void)n_in; (void)out_size; (void)ws_size;
  const float* query = (const float*)d_in[0];
  const float* key   = (const float*)d_in[1];
  const float* value = (const float*)d_in[2];
  const float* Wq = (const float*)d_in[3];
  const float* bq = (const float*)d_in[4];
  const float* Wk = (const float*)d_in[5];
  const float* bk = (const float*)d_in[6];
  const float* Wv = (const float*)d_in[7];
  const float* bv = (const float*)d_in[8];
  const float* Wo = (const float*)d_in[9];
  const float* bo = (const float*)d_in[10];

  char* base = (char*)d_ws;
  size_t off = 0;
  auto take = [&](size_t nbytes) -> char* {
    char* p = base + off;
    off += (nbytes + 255) & ~(size_t)255;
    return p;
  };
  const size_t LE2 = (size_t)L_SEQ * EDIM * 2;
  const size_t EE2 = (size_t)EDIM * EDIM * 2;
  bf16* wqb = (bf16*)take(EE2);
  bf16* wkb = (bf16*)take(EE2);
  bf16* wvb = (bf16*)take(EE2);
  bf16* wob = (bf16*)take(EE2);
  bf16* qb  = (bf16*)take(LE2);
  bf16* kb  = (bf16*)take(LE2);
  bf16* vb  = (bf16*)take(LE2);
  bf16* o0  = (bf16*)take(LE2);
  bf16* o1  = (bf16*)take(LE2);
  bf16* o2  = (bf16*)take(LE2);
  bf16* vt0 = (bf16*)take((size_t)4 * NH * HD * GLEN * 2);
  bf16* vt1 = (bf16*)take((size_t)2 * NH * HD * GLEN * 2);
  bf16* vt2 = (bf16*)take((size_t)1 * NH * HD * GLEN * 2);
  float* lse0 = (float*)take((size_t)NH * L_SEQ * 4);
  float* lse1 = (float*)take((size_t)NH * L_SEQ * 4);
  float* lse2 = (float*)take((size_t)NH * L_SEQ * 4);
  bf16* merged = (bf16*)take(LE2);

  dim3 blk(256);
  cvt_kernel<<<dim3(512, 4), blk, 0, stream>>>(
      Wq, Wk, Wv, Wo, wqb, wkb, wvb, wob);
  gemm_qkv_kernel<<<dim3(8, 32, 3), blk, 0, stream>>>(
      query, key, value, wqb, wkb, wvb, bq, bk, bv, qb, kb, vb);
  vtrans_kernel<<<dim3(1792), blk, 0, stream>>>(vb, vt0, vt1, vt2);
  attn_kernel<<<dim3(896), blk, 0, stream>>>(
      qb, kb, vt0, vt1, vt2, o0, o1, o2, lse0, lse1, lse2);
  merge_kernel<<<dim3(2048), blk, 0, stream>>>(
      o0, o1, o2, lse0, lse1, lse2, merged);
  gemm_out_kernel<<<dim3(8, 32), blk, 0, stream>>>(merged, wob, bo, (float*)d_out);
}

// Round 6
// 228.822 us; speedup vs baseline: 1.0513x; 1.0513x over previous
//
#include <hip/hip_runtime.h>
#include <math.h>

// DilatedAttention on MI355X (gfx950), bf16 MFMA implementation.
// L=4096, E=1024, H=16, D=64. Branches (sl,dr) = (1024,1),(2048,2),(4096,4).
// Every branch reduces to causal attention over g=1024 sparse positions.
//
// Attention in transposed-S form:
//   S^T = K Q^T  (lane l16 = q column)
//   O^T = V^T P^T with 16x16x16 MFMA    -> P^T registers are the B-operand.
// R4: XOR-swizzled LDS tiles via staging-source permutation.
// R5: q-tile PAIR (j, 15-j) per block: exactly 17 tile-computes each.
// exp2-domain softmax, defer-rescale, XCD-affinity attn remap.
// R6: fused dual-tile compute (shared K/V fragments, interleaved chains).
// R7: GEMM XCD-affinity remap; V^T pair-permuted (PV bank conflicts -> 0).
// R8: attn l-sum via ones-MFMA; setprio removed (measured regression).
// R9 (FAILED, reverted): fused fp32->bf16 A-conversion in gemm_qkv. Both
// variants (critical-path cvt 57us, dbuf cvt 66us) lost vs split cvt (44us):
// __syncthreads drains vmcnt(0), so "in-flight" A-reg loads serialize at the
// same barrier; cvt work lands on the critical path either way.
// R10: revert to split cvt (R7 structure) + T3-minimum dbuf 2-phase GEMM
// loop: stage(next-buf) BEFORE ds_read+MFMA, ONE barrier/iter -- staged
// loads get a full compute phase to land before their drain (catalog
// m248v2: +10% same-probe; vs m97-style stage-between-barriers which
// exposes full L2 latency every K-step).

#define L_SEQ 4096
#define EDIM  1024
#define NH    16
#define HD    64
#define GLEN  1024

typedef __bf16 bf16;
typedef __bf16 bf16x8 __attribute__((ext_vector_type(8)));
typedef __bf16 bf16x4 __attribute__((ext_vector_type(4)));
typedef short  s16x4  __attribute__((ext_vector_type(4)));
typedef float  f32x4  __attribute__((ext_vector_type(4)));

template <bool B> struct Flag { static constexpr bool v = B; };

// async global->LDS, 16B per lane. LDS dest semantics: wave-uniform base + lane*16.
__device__ __forceinline__ void gload16(const bf16* g, bf16* l) {
  __builtin_amdgcn_global_load_lds(
      (__attribute__((address_space(1))) void*)(const_cast<bf16*>(g)),
      (__attribute__((address_space(3))) void*)(l),
      16, 0, 0);
}

// v_mfma_f32_16x16x16_bf16 (builtin name only exists in the device pass).
__device__ __forceinline__ f32x4 mfma16x16x16_bf16(bf16x4 a, bf16x4 b, f32x4 c) {
#if defined(__HIP_DEVICE_COMPILE__)
  union { bf16x4 h; s16x4 s; } ua, ub;
  ua.h = a; ub.h = b;
  return __builtin_amdgcn_mfma_f32_16x16x16bf16_1k(ua.s, ub.s, c, 0, 0, 0);
#else
  (void)a; (void)b;
  return c;   // host stub, never executed
#endif
}

__device__ __forceinline__ float fast_exp2(float x) {
#if __has_builtin(__builtin_amdgcn_exp2f)
  return __builtin_amdgcn_exp2f(x);
#else
  return __expf(x * 0.6931471805599453f);
#endif
}

// ---------------------------------------------------------------------------
// fp32 -> bf16 conversion for query/key/value (L*E) and Wq/Wk/Wv/Wo (E*E)
// ---------------------------------------------------------------------------
__global__ __launch_bounds__(256) void cvt_kernel(
    const float* q, const float* k, const float* v,
    const float* wq, const float* wk, const float* wv, const float* wo,
    bf16* oq, bf16* ok, bf16* ov,
    bf16* owq, bf16* owk, bf16* owv, bf16* owo)
{
  const float* src; bf16* dst; int n;
  switch (blockIdx.y) {
    case 0: src = q;  dst = oq;  n = L_SEQ*EDIM; break;
    case 1: src = k;  dst = ok;  n = L_SEQ*EDIM; break;
    case 2: src = v;  dst = ov;  n = L_SEQ*EDIM; break;
    case 3: src = wq; dst = owq; n = EDIM*EDIM; break;
    case 4: src = wk; dst = owk; n = EDIM*EDIM; break;
    case 5: src = wv; dst = owv; n = EDIM*EDIM; break;
    default: src = wo; dst = owo; n = EDIM*EDIM; break;
  }
  int i = (blockIdx.x * 256 + threadIdx.x) * 8;
  if (i >= n) return;
  const float4* s4 = (const float4*)(src + i);
  float4 a = s4[0], b = s4[1];
  bf16x8 o = { (bf16)a.x, (bf16)a.y, (bf16)a.z, (bf16)a.w,
               (bf16)b.x, (bf16)b.y, (bf16)b.z, (bf16)b.w };
  *(bf16x8*)(dst + i) = o;
}

// ---------------------------------------------------------------------------
// GEMM: C[m][n] = sum_k A[m][k] * W[n][k] + bias[n]   (B^T layout)
// M=4096, N=1024, K=1024. 128x128 tile, BK=32, 4 waves (2x2 of 64x64),
// 16x16x32 bf16 MFMA. T3-minimum dbuf 2-phase: stage(next buf) issued
// BEFORE ds_read+MFMA of current buf; ONE barrier per K-step (drains the
// in-flight loads, which had the whole compute phase to land).
// Grid MUST be (8, 32[, z]); XCD-affinity: HW XCD = flat%8 = blockIdx.x;
// XCD x owns row-panels [x*4, x*4+4) (A panels hit one XCD L2).
// ---------------------------------------------------------------------------
template <typename OutT>
__device__ __forceinline__ void gemm_body(const bf16* __restrict__ A,
                                          const bf16* __restrict__ W,
                                          const float* __restrict__ bias,
                                          OutT* __restrict__ C)
{
  constexpr int K = 1024;
  __shared__ __align__(16) bf16 lA[2][128 * 32];
  __shared__ __align__(16) bf16 lB[2][128 * 32];

  const int tid  = threadIdx.x;
  const int lane = tid & 63;
  const int w    = tid >> 6;
  const int quad = lane >> 4;
  const int l16  = lane & 15;
  const int wr   = w >> 1, wc = w & 1;
  // XCD-affinity remap (bijective over 8x32): ly=x*4+(y>>3), lx=y&7
  const int ly = blockIdx.x * 4 + (blockIdx.y >> 3);
  const int lx = blockIdx.y & 7;
  const int row0 = ly * 128;
  const int col0 = lx * 128;

  f32x4 acc[4][4] = {};

  const int c0 = tid, c1 = tid + 256;
  const bf16* Ab0 = A + (size_t)(row0 + (c0 >> 2)) * K + (c0 & 3) * 8;
  const bf16* Ab1 = A + (size_t)(row0 + (c1 >> 2)) * K + (c1 & 3) * 8;
  const bf16* Bb0 = W + (size_t)(col0 + (c0 >> 2)) * K + (c0 & 3) * 8;
  const bf16* Bb1 = W + (size_t)(col0 + (c1 >> 2)) * K + (c1 & 3) * 8;

  auto stage = [&](int kt, int buf) {
    gload16(Ab0 + kt, &lA[buf][c0 * 8]);
    gload16(Ab1 + kt, &lA[buf][c1 * 8]);
    gload16(Bb0 + kt, &lB[buf][c0 * 8]);
    gload16(Bb1 + kt, &lB[buf][c1 * 8]);
  };

  stage(0, 0);
  __syncthreads();                        // buf0 resident

  for (int t = 0; t < 32; ++t) {
    const int cur = t & 1;
    if (t < 31) stage((t + 1) * 32, cur ^ 1);   // issue first: in flight under MFMA

    bf16x8 af[4], bfrag[4];
#pragma unroll
    for (int mi = 0; mi < 4; mi++)
      af[mi] = *(const bf16x8*)&lA[cur][(wr * 64 + mi * 16 + l16) * 32 + quad * 8];
#pragma unroll
    for (int ni = 0; ni < 4; ni++)
      bfrag[ni] = *(const bf16x8*)&lB[cur][(wc * 64 + ni * 16 + l16) * 32 + quad * 8];
#pragma unroll
    for (int mi = 0; mi < 4; mi++)
#pragma unroll
      for (int ni = 0; ni < 4; ni++)
        acc[mi][ni] = __builtin_amdgcn_mfma_f32_16x16x32_bf16(
            af[mi], bfrag[ni], acc[mi][ni], 0, 0, 0);

    __syncthreads();   // drains next-buf loads (landed under compute); frees cur
  }

#pragma unroll
  for (int mi = 0; mi < 4; mi++) {
#pragma unroll
    for (int ni = 0; ni < 4; ni++) {
      const int gcol = col0 + wc * 64 + ni * 16 + l16;
      const float bv = bias[gcol];
#pragma unroll
      for (int r = 0; r < 4; r++) {
        const int grow = row0 + wr * 64 + mi * 16 + quad * 4 + r;
        C[(size_t)grow * 1024 + gcol] = (OutT)(acc[mi][ni][r] + bv);
      }
    }
  }
}

__global__ __launch_bounds__(256) void gemm_qkv_kernel(
    const bf16* xq, const bf16* xk, const bf16* xv,
    const bf16* wq, const bf16* wk, const bf16* wv,
    const float* bq, const float* bk, const float* bv,
    bf16* q, bf16* k, bf16* v)
{
  const bf16 *A, *W; const float* bias; bf16* C;
  if (blockIdx.z == 0)      { A = xq; W = wq; bias = bq; C = q; }
  else if (blockIdx.z == 1) { A = xk; W = wk; bias = bk; C = k; }
  else                      { A = xv; W = wv; bias = bv; C = v; }
  gemm_body<bf16>(A, W, bias, C);
}

__global__ __launch_bounds__(256) void gemm_out_kernel(
    const bf16* A, const bf16* W, const float* bias, float* C)
{
  gemm_body<float>(A, W, bias, C);
}

// ---------------------------------------------------------------------------
// V transpose into per-branch sparse-contiguous layout: vt_b[seg][h][d][kj'].
// kj' is PAIR-PERMUTED within each 64-kpos tile-row: chunk c' = p2*4 + q
// (p2 in {0,1}, q in {0..3}) holds old kpos {p2*32+q*4..+4} ++
// {p2*32+16+q*4..+4}, so one 16B read serves MFMA pair (t=2p2, 2p2+1).
// ---------------------------------------------------------------------------
__global__ __launch_bounds__(256) void vtrans_kernel(
    const bf16* __restrict__ v, bf16* vt0, bf16* vt1, bf16* vt2)
{
  __shared__ __align__(16) bf16 ltile[64 * 72];   // [kj][d], padded
  const int bid = blockIdx.x;
  int sl, dr, rem, shift; bf16* vt;
  if (bid < 1024)      { sl = 1024; dr = 1; rem = bid;        vt = vt0; shift = 4; }
  else if (bid < 1536) { sl = 2048; dr = 2; rem = bid - 1024; vt = vt1; shift = 3; }
  else                 { sl = 4096; dr = 4; rem = bid - 1536; vt = vt2; shift = 2; }
  const int ktile = rem & 15;
  const int h     = (rem >> 4) & 15;
  const int seg   = rem >> 8;
  const int grp   = h >> shift;          // h / (16/dr)
  const int segbase = seg * sl;
  const int tid = threadIdx.x;
  {
    const int i = tid >> 2, dc = tid & 3;
    const size_t p = (size_t)(segbase + (ktile * 64 + i) * dr + grp);
    const bf16* src = v + p * EDIM + h * 64 + dc * 16;
    *(uint4*)&ltile[i * 72 + dc * 16]     = *(const uint4*)(src);
    *(uint4*)&ltile[i * 72 + dc * 16 + 8] = *(const uint4*)(src + 8);
  }
  __syncthreads();
  {
    const int d = tid >> 2, kc = tid & 3;   // kc = t (old 16-kpos group)
    __align__(16) bf16 tmp[16];
#pragma unroll
    for (int j = 0; j < 16; j++) tmp[j] = ltile[(kc * 16 + j) * 72 + d];
    // pair-permuted destination: newpos = p2*32 + q*8 + half*4 + r
    const int p2 = kc >> 1, half = kc & 1;
    bf16* dst = vt + ((size_t)(seg * NH + h) * 64 + d) * GLEN + ktile * 64
                   + p2 * 32 + half * 4;
#pragma unroll
    for (int q = 0; q < 4; q++) {
      bf16x4 piece = { tmp[q * 4 + 0], tmp[q * 4 + 1],
                       tmp[q * 4 + 2], tmp[q * 4 + 3] };
      *(bf16x4*)(dst + q * 8) = piece;
    }
  }
}

// ---------------------------------------------------------------------------
// Flash attention, transposed-S form with XOR-swizzled LDS tiles.
// Block = (branch, seg, h, pair j): q-tiles qtA = 15-j and qtB = j over one
// shared staged K/V stream. Dual-tile fused compute: both tiles consume the
// SAME K/V fragments, softmax chains interleave. l-sum via ones-MFMA.
// ---------------------------------------------------------------------------
__global__ __launch_bounds__(256, 4) void attn_kernel(
    const bf16* __restrict__ qg, const bf16* __restrict__ kg,
    const bf16* vt0, const bf16* vt1, const bf16* vt2,
    bf16* o0, bf16* o1, bf16* o2,
    float* l0, float* l1, float* l2)
{
  __shared__ __align__(16) bf16 lK[2][64 * 64];     // [kj][d], swizzled
  __shared__ __align__(16) bf16 lV[2][64 * 64];     // [d][kj'], swizzled

  // XCD-affinity remap (bijective, 896 = 8*112): hardware assigns block b to
  // XCD b%8; logical id o = (b&7)*112 + (b>>3) gives each XCD a contiguous
  // run of 112 logical blocks = 14 (seg,h) groups -> K/V fits that XCD's L2.
  const int bid0 = blockIdx.x;
  const int o = (bid0 & 7) * 112 + (bid0 >> 3);

  int sl, dr, rem, shift;
  const bf16* vt; bf16* ob; float* lseb;
  if (o < 512)      { sl = 1024; dr = 1; rem = o;       vt = vt0; ob = o0; lseb = l0; shift = 4; }
  else if (o < 768) { sl = 2048; dr = 2; rem = o - 512; vt = vt1; ob = o1; lseb = l1; shift = 3; }
  else              { sl = 4096; dr = 4; rem = o - 768; vt = vt2; ob = o2; lseb = l2; shift = 2; }
  const int j   = rem & 7;
  const int h   = (rem >> 3) & 15;
  const int seg = rem >> 7;
  const int qtA = 15 - j;                // high q-tile (16-j k-iterations)
  const int qtB = j;                     // low q-tile  (j+1 k-iterations); qtB < qtA
  const int grp = h >> shift;
  const int segbase = seg * sl;

  const int tid = threadIdx.x, lane = tid & 63, w = tid >> 6;
  const int quad = lane >> 4, l16 = lane & 15;
  const int rs8 = l16 & 7;               // row-XOR term: (kj&7)==(drow&7)==l16&7

  // Q fragments (B-operand of S^T MFMA): B[k=d=quad*8+j][n=q=l16]
  auto loadq = [&](int qt, bf16x8& a0, bf16x8& a1) {
    const int qi = qt * 64 + w * 16 + l16;
    const size_t p = (size_t)(segbase + qi * dr + grp);
    const bf16* qp = qg + p * EDIM + h * 64 + quad * 8;
    a0 = *(const bf16x8*)(qp);
    a1 = *(const bf16x8*)(qp + 32);
  };
  bf16x8 qaA0, qaA1, qaB0, qaB1;
  loadq(qtA, qaA0, qaA1);
  loadq(qtB, qaB0, qaB1);

  f32x4 OA[4] = {}, OB[4] = {};          // O^T frags: col l16=q, row = d
  f32x4 lsA = {0.f, 0.f, 0.f, 0.f};      // l accumulated by ones-MFMA
  f32x4 lsB = {0.f, 0.f, 0.f, 0.f};
  float mA = -__builtin_inff();          // m in log2 units
  float mB = -__builtin_inff();
  const bf16x4 ONES = { (bf16)1.f, (bf16)1.f, (bf16)1.f, (bf16)1.f };

  const bf16* vbase = vt + (size_t)(seg * NH + h) * 64 * GLEN;
  const int c0 = tid, c1 = tid + 256;
  // staging-source permutation implementing the XOR swizzle:
  // LDS chunk position p (=c0/c1) is row r=p>>3, slot s=p&7; it must receive
  // global chunk c = s ^ (r & 7).
  const int r0 = c0 >> 3, sw0 = ((c0 & 7) ^ (r0 & 7));
  const int r1 = c1 >> 3, sw1 = ((c1 & 7) ^ (r1 & 7));

  // incremental staging pointers (advance one k-tile per stage call)
  const bf16* kp0 = kg + (size_t)(segbase + r0 * dr + grp) * EDIM + h * 64 + sw0 * 8;
  const bf16* kp1 = kg + (size_t)(segbase + r1 * dr + grp) * EDIM + h * 64 + sw1 * 8;
  const bf16* vp0 = vbase + (size_t)r0 * GLEN + sw0 * 8;
  const bf16* vp1 = vbase + (size_t)r1 * GLEN + sw1 * 8;
  const size_t kstep = (size_t)64 * dr * EDIM;

  auto stage = [&](int buf) {
    gload16(kp0, &lK[buf][c0 * 8]);
    gload16(kp1, &lK[buf][c1 * 8]);
    gload16(vp0, &lV[buf][c0 * 8]);
    gload16(vp1, &lV[buf][c1 * 8]);
    kp0 += kstep; kp1 += kstep; vp0 += 64; vp1 += 64;
  };

  const float CS = 0.18033688011112042f;   // (1/sqrt(64)) * log2(e)
  const float NEGINF = -__builtin_inff();
  const int qiA = qtA * 64 + w * 16 + l16;
  const int qiB = qtB * 64 + w * 16 + l16;

  // loop-invariant LDS read bases (K: kj = t*16+l16 -> +t*1024; V: +nf*1024)
  const int kb0 = l16 * 64 + ((quad ^ rs8) * 8);
  const int kb1 = l16 * 64 + (((4 + quad) ^ rs8) * 8);
  const int vb0 = l16 * 64;

  // Fused dual-tile compute. HAS_B: tile B active this k-tile. DIAG_A/B:
  // causal-diagonal masking for that tile (DIAG_A implies !HAS_B).
  auto comp = [&](auto hasB_, auto diagA_, auto diagB_, int kt) {
    constexpr bool HAS_B  = decltype(hasB_)::v;
    constexpr bool DIAG_A = decltype(diagA_)::v;
    constexpr bool DIAG_B = decltype(diagB_)::v;
    const bf16* bK = lK[kt & 1];
    const bf16* bV = lV[kt & 1];

    // --- S^T = K Q^T for both tiles off shared K fragments ---
    f32x4 sA[4], sB[4];
#pragma unroll
    for (int t = 0; t < 4; t++) {
      const bool aA = !DIAG_A || t <= w;
      const bool aB = HAS_B && (!DIAG_B || t <= w);
      if (aA || aB) {
        bf16x8 ka0 = *(const bf16x8*)&bK[kb0 + t * 1024];
        bf16x8 ka1 = *(const bf16x8*)&bK[kb1 + t * 1024];
        if (aA) {
          sA[t] = f32x4{0.f, 0.f, 0.f, 0.f};
          sA[t] = __builtin_amdgcn_mfma_f32_16x16x32_bf16(ka0, qaA0, sA[t], 0, 0, 0);
          sA[t] = __builtin_amdgcn_mfma_f32_16x16x32_bf16(ka1, qaA1, sA[t], 0, 0, 0);
        }
        if (aB) {
          sB[t] = f32x4{0.f, 0.f, 0.f, 0.f};
          sB[t] = __builtin_amdgcn_mfma_f32_16x16x32_bf16(ka0, qaB0, sB[t], 0, 0, 0);
          sB[t] = __builtin_amdgcn_mfma_f32_16x16x32_bf16(ka1, qaB1, sB[t], 0, 0, 0);
        }
      }
    }

    // --- masked raw max, vector partials ---
    f32x4 mvA = {NEGINF, NEGINF, NEGINF, NEGINF};
    f32x4 mvB = {NEGINF, NEGINF, NEGINF, NEGINF};
#pragma unroll
    for (int t = 0; t < 4; t++) {
      if (!DIAG_A || t <= w) {
#pragma unroll
        for (int r = 0; r < 4; r++) {
          float sv = sA[t][r];
          if (DIAG_A) {
            const int kj = kt * 64 + t * 16 + quad * 4 + r;
            if (kj > qiA) sv = NEGINF;
          }
          sA[t][r] = sv;
          mvA[r] = fmaxf(mvA[r], sv);
        }
      }
      if (HAS_B && (!DIAG_B || t <= w)) {
#pragma unroll
        for (int r = 0; r < 4; r++) {
          float sv = sB[t][r];
          if (DIAG_B) {
            const int kj = kt * 64 + t * 16 + quad * 4 + r;
            if (kj > qiB) sv = NEGINF;
          }
          sB[t][r] = sv;
          mvB[r] = fmaxf(mvB[r], sv);
        }
      }
    }
    float mrA = fmaxf(fmaxf(mvA[0], mvA[1]), fmaxf(mvA[2], mvA[3]));
    float mrB = fmaxf(fmaxf(mvB[0], mvB[1]), fmaxf(mvB[2], mvB[3]));
    mrA = fmaxf(mrA, __shfl_xor(mrA, 16, 64));
    mrA = fmaxf(mrA, __shfl_xor(mrA, 32, 64));
    if constexpr (HAS_B) {
      mrB = fmaxf(mrB, __shfl_xor(mrB, 16, 64));
      mrB = fmaxf(mrB, __shfl_xor(mrB, 32, 64));
    }

    // --- defer-rescale (T13), wave-uniform skip ---
    {
      const float mnew = fmaxf(mA, mrA * CS);
      if (!__all(mnew - mA <= 8.0f)) {
        const float alpha = fast_exp2(mA - mnew);   // first tile: exp2(-inf)=0
#pragma unroll
        for (int nf = 0; nf < 4; nf++)
#pragma unroll
          for (int r = 0; r < 4; r++) OA[nf][r] *= alpha;
#pragma unroll
        for (int r = 0; r < 4; r++) lsA[r] *= alpha;
        mA = mnew;
      }
    }
    if constexpr (HAS_B) {
      const float mnew = fmaxf(mB, mrB * CS);
      if (!__all(mnew - mB <= 8.0f)) {
        const float alpha = fast_exp2(mB - mnew);
#pragma unroll
        for (int nf = 0; nf < 4; nf++)
#pragma unroll
          for (int r = 0; r < 4; r++) OB[nf][r] *= alpha;
#pragma unroll
        for (int r = 0; r < 4; r++) lsB[r] *= alpha;
        mB = mnew;
      }
    }

    // --- p = exp2(fma(s_raw, CS, -m)) <= 2^8; bf16 pack ---
    bf16x4 pbA[4], pbB[4];
#pragma unroll
    for (int t = 0; t < 4; t++) {
      if (!DIAG_A || t <= w) {
#pragma unroll
        for (int r = 0; r < 4; r++)
          pbA[t][r] = (bf16)fast_exp2(__builtin_fmaf(sA[t][r], CS, -mA));
      }
      if (HAS_B && (!DIAG_B || t <= w)) {
#pragma unroll
        for (int r = 0; r < 4; r++)
          pbB[t][r] = (bf16)fast_exp2(__builtin_fmaf(sB[t][r], CS, -mB));
      }
    }

    // --- O^T += V^T P^T off shared V fragments (paired b128 reads);
    //     l += ones-MFMA(P^T): full 64-kpos row sum incl. cross-quad ---
#pragma unroll
    for (int p2 = 0; p2 < 2; p2++) {
      const int t0 = 2 * p2, t1 = t0 + 1;
      const bool aA0 = !DIAG_A || t0 <= w;
      const bool aA1 = !DIAG_A || t1 <= w;
      const bool aB0 = HAS_B && (!DIAG_B || t0 <= w);
      const bool aB1 = HAS_B && (!DIAG_B || t1 <= w);
      if (aA0 || aA1 || aB0 || aB1) {
        const int cx = ((p2 * 4 + quad) ^ rs8) * 8;
#pragma unroll
        for (int nf = 0; nf < 4; nf++) {
          bf16x8 va8 = *(const bf16x8*)&bV[vb0 + nf * 1024 + cx];
          bf16x4 vlo = __builtin_shufflevector(va8, va8, 0, 1, 2, 3);
          bf16x4 vhi = __builtin_shufflevector(va8, va8, 4, 5, 6, 7);
          if (aA0) OA[nf] = mfma16x16x16_bf16(vlo, pbA[t0], OA[nf]);
          if (aA1) OA[nf] = mfma16x16x16_bf16(vhi, pbA[t1], OA[nf]);
          if (aB0) OB[nf] = mfma16x16x16_bf16(vlo, pbB[t0], OB[nf]);
          if (aB1) OB[nf] = mfma16x16x16_bf16(vhi, pbB[t1], OB[nf]);
        }
        if (aA0) lsA = mfma16x16x16_bf16(ONES, pbA[t0], lsA);
        if (aA1) lsA = mfma16x16x16_bf16(ONES, pbA[t1], lsA);
        if (aB0) lsB = mfma16x16x16_bf16(ONES, pbB[t0], lsB);
        if (aB1) lsB = mfma16x16x16_bf16(ONES, pbB[t1], lsB);
      }
    }
  };

  stage(0);
  int kt = 0;
  // Phase 1: both tiles, no diagonal (kt < qtB)
  for (; kt < qtB; kt++) {
    __syncthreads();
    stage((kt + 1) & 1);
    comp(Flag<true>{}, Flag<false>{}, Flag<false>{}, kt);
  }
  // kt == qtB: tile A full, tile B diagonal (qtB < qtA always)
  __syncthreads();
  stage((kt + 1) & 1);
  comp(Flag<true>{}, Flag<false>{}, Flag<true>{}, kt);
  kt++;
  // Phase 2: tile A only (qtB < kt < qtA)
  for (; kt < qtA; kt++) {
    __syncthreads();
    stage((kt + 1) & 1);
    comp(Flag<false>{}, Flag<false>{}, Flag<false>{}, kt);
  }
  // kt == qtA: tile A diagonal
  __syncthreads();
  comp(Flag<false>{}, Flag<true>{}, Flag<false>{}, kt);

  // epilogue: lane l16 owns q column; d = nf*16 + quad*4 + r (4 contiguous)
  auto epilogue = [&](const f32x4 (&Oa)[4], float m_r, float l_r, int qt) {
    const int qi = qt * 64 + w * 16 + l16;
    const float linv = 1.0f / l_r;
    const int pdense = segbase + qi * dr + grp;
    bf16* orow = ob + (size_t)pdense * EDIM + h * 64;
#pragma unroll
    for (int nf = 0; nf < 4; nf++) {
      bf16x4 ov;
#pragma unroll
      for (int r = 0; r < 4; r++) ov[r] = (bf16)(Oa[nf][r] * linv);
      *(bf16x4*)(orow + nf * 16 + quad * 4) = ov;
    }
    if (quad == 0)
      lseb[h * L_SEQ + pdense] = m_r * 0.6931471805599453f + __logf(l_r);
  };
  epilogue(OA, mA, lsA[0], qtA);
  epilogue(OB, mB, lsB[0], qtB);
}

// ---------------------------------------------------------------------------
// Merge: softmax over branch lse at each (h,p); coverage computed analytically.
// ---------------------------------------------------------------------------
__global__ __launch_bounds__(256) void merge_kernel(
    const bf16* __restrict__ o0, const bf16* __restrict__ o1, const bf16* __restrict__ o2,
    const float* __restrict__ l0, const float* __restrict__ l1, const float* __restrict__ l2,
    bf16* __restrict__ merged)
{
  const int idx = blockIdx.x * 256 + threadIdx.x;   // over L*H*8
  const int dc = idx & 7;
  const int h  = (idx >> 3) & 15;
  const int p  = idx >> 7;
  const bool c1 = ((p & 1) == (h >> 3));   // branch dr=2 coverage
  const bool c2 = ((p & 3) == (h >> 2));   // branch dr=4 coverage
  const float s0 = l0[h * L_SEQ + p];
  const float s1 = c1 ? l1[h * L_SEQ + p] : -__builtin_inff();
  const float s2 = c2 ? l2[h * L_SEQ + p] : -__builtin_inff();
  const float mx = fmaxf(s0, fmaxf(s1, s2));
  float w0 = __expf(s0 - mx);
  float w1 = c1 ? __expf(s1 - mx) : 0.f;
  float w2 = c2 ? __expf(s2 - mx) : 0.f;
  const float inv = 1.0f / (w0 + w1 + w2);
  w0 *= inv; w1 *= inv; w2 *= inv;

  const size_t off = (size_t)p * EDIM + h * 64 + dc * 8;
  float acc[8];
  bf16x8 a0 = *(const bf16x8*)(o0 + off);
#pragma unroll
  for (int j = 0; j < 8; j++) acc[j] = w0 * (float)a0[j];
  if (c1) {
    bf16x8 a1 = *(const bf16x8*)(o1 + off);
#pragma unroll
    for (int j = 0; j < 8; j++) acc[j] += w1 * (float)a1[j];
  }
  if (c2) {
    bf16x8 a2 = *(const bf16x8*)(o2 + off);
#pragma unroll
    for (int j = 0; j < 8; j++) acc[j] += w2 * (float)a2[j];
  }
  bf16x8 r;
#pragma unroll
  for (int j = 0; j < 8; j++) r[j] = (bf16)acc[j];
  *(bf16x8*)(merged + off) = r;
}

// ---------------------------------------------------------------------------
extern "C" void kernel_launch(void* const* d_in, const int* in_sizes, int n_in,
                              void* d_out, int out_size, void* d_ws, size_t ws_size,
                              hipStream_t stream)
{
  (void)in_sizes; (void)n_in; (void)out_size; (void)ws_size;
  const float* query = (const float*)d_in[0];
  const float* key   = (const float*)d_in[1];
  const float* value = (const float*)d_in[2];
  const float* Wq = (const float*)d_in[3];
  const float* bq = (const float*)d_in[4];
  const float* Wk = (const float*)d_in[5];
  const float* bk = (const float*)d_in[6];
  const float* Wv = (const float*)d_in[7];
  const float* bv = (const float*)d_in[8];
  const float* Wo = (const float*)d_in[9];
  const float* bo = (const float*)d_in[10];

  char* base = (char*)d_ws;
  size_t off = 0;
  auto take = [&](size_t nbytes) -> char* {
    char* p = base + off;
    off += (nbytes + 255) & ~(size_t)255;
    return p;
  };
  const size_t LE2 = (size_t)L_SEQ * EDIM * 2;
  const size_t EE2 = (size_t)EDIM * EDIM * 2;
  bf16* xq  = (bf16*)take(LE2);
  bf16* xk  = (bf16*)take(LE2);
  bf16* xv  = (bf16*)take(LE2);
  bf16* wqb = (bf16*)take(EE2);
  bf16* wkb = (bf16*)take(EE2);
  bf16* wvb = (bf16*)take(EE2);
  bf16* wob = (bf16*)take(EE2);
  bf16* qb  = (bf16*)take(LE2);
  bf16* kb  = (bf16*)take(LE2);
  bf16* vb  = (bf16*)take(LE2);
  bf16* vt0 = (bf16*)take((size_t)4 * NH * HD * GLEN * 2);
  bf16* vt1 = (bf16*)take((size_t)2 * NH * HD * GLEN * 2);
  bf16* vt2 = (bf16*)take((size_t)1 * NH * HD * GLEN * 2);
  float* lse0 = (float*)take((size_t)NH * L_SEQ * 4);
  float* lse1 = (float*)take((size_t)NH * L_SEQ * 4);
  float* lse2 = (float*)take((size_t)NH * L_SEQ * 4);
  bf16* merged = (bf16*)take(LE2);
  // branch outputs alias the converted inputs (dead after gemm_qkv)
  bf16* o0 = xq; bf16* o1 = xk; bf16* o2 = xv;

  dim3 blk(256);
  cvt_kernel<<<dim3(2048, 7), blk, 0, stream>>>(
      query, key, value, Wq, Wk, Wv, Wo, xq, xk, xv, wqb, wkb, wvb, wob);
  gemm_qkv_kernel<<<dim3(8, 32, 3), blk, 0, stream>>>(
      xq, xk, xv, wqb, wkb, wvb, bq, bk, bv, qb, kb, vb);
  vtrans_kernel<<<dim3(1792), blk, 0, stream>>>(vb, vt0, vt1, vt2);
  attn_kernel<<<dim3(896), blk, 0, stream>>>(
      qb, kb, vt0, vt1, vt2, o0, o1, o2, lse0, lse1, lse2);
  merge_kernel<<<dim3(2048), blk, 0, stream>>>(
      o0, o1, o2, lse0, lse1, lse2, merged);
  gemm_out_kernel<<<dim3(8, 32), blk, 0, stream>>>(merged, wob, bo, (float*)d_out);
}

// Round 7
// 227.609 us; speedup vs baseline: 1.0569x; 1.0053x over previous
//
#include <hip/hip_runtime.h>
#include <math.h>

// DilatedAttention on MI355X (gfx950), bf16 MFMA implementation.
// L=4096, E=1024, H=16, D=64. Branches (sl,dr) = (1024,1),(2048,2),(4096,4).
// Every branch reduces to causal attention over g=1024 sparse positions.
//
// Attention in transposed-S form:
//   S^T = K Q^T  (lane l16 = q column)
//   O^T = V^T P^T with 16x16x16 MFMA    -> P^T registers are the B-operand.
// R4: XOR-swizzled LDS tiles via staging-source permutation.
// R5: q-tile PAIR (j, 15-j) per block: exactly 17 tile-computes each.
// exp2-domain softmax, defer-rescale, XCD-affinity attn remap.
// R6: fused dual-tile compute (shared K/V fragments, interleaved chains).
// R7: GEMM XCD-affinity remap; V^T pair-permuted (PV bank conflicts -> 0).
// R8: attn l-sum via ones-MFMA; setprio removed (measured regression).
// R9 (FAILED, reverted): fused fp32->bf16 A-conv in gemm_qkv critical path.
// R10 (NULL): T3-minimum 2-buffer stage-early -- null because one K-step is
// only 16 MFMA (~78cyc) vs ~200cyc L2 latency, and __syncthreads drains
// vmcnt(0) anyway, exposing the in-flight load at every barrier.
// R11: TRUE counted-vmcnt pipeline (T4, the catalog's proven lever): 3 LDS
// buffers, 2-deep prefetch, raw s_barrier + s_waitcnt vmcnt(4) -- stage(t+2)
// stays IN FLIGHT across the barrier while stage(t+1) (needed next) is
// drained. Each tile gets 2 compute phases + cross-wave TLP to cover L2
// latency. LDS 48KB = exactly the 3 blocks/CU the grid needs. Tail peeled
// (vmcnt(0) at t=30). cvt grid exact-cover 1D (8192 blocks, no empty waves).

#define L_SEQ 4096
#define EDIM  1024
#define NH    16
#define HD    64
#define GLEN  1024

typedef __bf16 bf16;
typedef __bf16 bf16x8 __attribute__((ext_vector_type(8)));
typedef __bf16 bf16x4 __attribute__((ext_vector_type(4)));
typedef short  s16x4  __attribute__((ext_vector_type(4)));
typedef float  f32x4  __attribute__((ext_vector_type(4)));

template <bool B> struct Flag { static constexpr bool v = B; };

// async global->LDS, 16B per lane. LDS dest semantics: wave-uniform base + lane*16.
__device__ __forceinline__ void gload16(const bf16* g, bf16* l) {
  __builtin_amdgcn_global_load_lds(
      (__attribute__((address_space(1))) void*)(const_cast<bf16*>(g)),
      (__attribute__((address_space(3))) void*)(l),
      16, 0, 0);
}

// v_mfma_f32_16x16x16_bf16 (builtin name only exists in the device pass).
__device__ __forceinline__ f32x4 mfma16x16x16_bf16(bf16x4 a, bf16x4 b, f32x4 c) {
#if defined(__HIP_DEVICE_COMPILE__)
  union { bf16x4 h; s16x4 s; } ua, ub;
  ua.h = a; ub.h = b;
  return __builtin_amdgcn_mfma_f32_16x16x16bf16_1k(ua.s, ub.s, c, 0, 0, 0);
#else
  (void)a; (void)b;
  return c;   // host stub, never executed
#endif
}

__device__ __forceinline__ float fast_exp2(float x) {
#if __has_builtin(__builtin_amdgcn_exp2f)
  return __builtin_amdgcn_exp2f(x);
#else
  return __expf(x * 0.6931471805599453f);
#endif
}

// ---------------------------------------------------------------------------
// fp32 -> bf16 conversion, exact-cover 1D grid (8192 blocks x 256 x 8 elems):
// elems [0,12M): q/k/v (4M=2^22 each); [12M,16M): Wq/Wk/Wv/Wo (1M=2^20 each).
// ---------------------------------------------------------------------------
__global__ __launch_bounds__(256) void cvt_kernel(
    const float* q, const float* k, const float* v,
    const float* wq, const float* wk, const float* wv, const float* wo,
    bf16* oq, bf16* ok, bf16* ov,
    bf16* owq, bf16* owk, bf16* owv, bf16* owo)
{
  const size_t e = ((size_t)blockIdx.x * 256 + threadIdx.x) * 8;
  const float* src; bf16* dst; size_t off;
  if (e < (size_t)12 * 1024 * 1024) {
    const int s = (int)(e >> 22);
    off = e & (((size_t)1 << 22) - 1);
    src = (s == 0) ? q : (s == 1) ? k : v;
    dst = (s == 0) ? oq : (s == 1) ? ok : ov;
  } else {
    const size_t e2 = e - (size_t)12 * 1024 * 1024;
    const int s = (int)(e2 >> 20);
    off = e2 & (((size_t)1 << 20) - 1);
    src = (s == 0) ? wq : (s == 1) ? wk : (s == 2) ? wv : wo;
    dst = (s == 0) ? owq : (s == 1) ? owk : (s == 2) ? owv : owo;
  }
  const float4* s4 = (const float4*)(src + off);
  float4 a = s4[0], b = s4[1];
  bf16x8 o = { (bf16)a.x, (bf16)a.y, (bf16)a.z, (bf16)a.w,
               (bf16)b.x, (bf16)b.y, (bf16)b.z, (bf16)b.w };
  *(bf16x8*)(dst + off) = o;
}

// ---------------------------------------------------------------------------
// GEMM: C[m][n] = sum_k A[m][k] * W[n][k] + bias[n]   (B^T layout)
// M=4096, N=1024, K=1024. 128x128 tile, BK=32, 4 waves (2x2 of 64x64),
// 16x16x32 bf16 MFMA. R11 counted-vmcnt pipeline: 3 LDS buffers, 2-deep
// prefetch; per iter: issue stage(t+2), compute tile t, then
// s_waitcnt vmcnt(4) (drain stage(t+1) ONLY -- stage(t+2) stays in flight
// across the raw s_barrier). Tail peeled with vmcnt(0).
// Grid MUST be (8, 32[, z]); XCD-affinity: HW XCD = flat%8 = blockIdx.x;
// XCD x owns row-panels [x*4, x*4+4) (A panels hit one XCD L2).
// ---------------------------------------------------------------------------
template <typename OutT>
__device__ __forceinline__ void gemm_body(const bf16* __restrict__ A,
                                          const bf16* __restrict__ W,
                                          const float* __restrict__ bias,
                                          OutT* __restrict__ C)
{
  constexpr int K = 1024;
  __shared__ __align__(16) bf16 lA[3][128 * 32];
  __shared__ __align__(16) bf16 lB[3][128 * 32];

  const int tid  = threadIdx.x;
  const int lane = tid & 63;
  const int w    = tid >> 6;
  const int quad = lane >> 4;
  const int l16  = lane & 15;
  const int wr   = w >> 1, wc = w & 1;
  // XCD-affinity remap (bijective over 8x32): ly=x*4+(y>>3), lx=y&7
  const int ly = blockIdx.x * 4 + (blockIdx.y >> 3);
  const int lx = blockIdx.y & 7;
  const int row0 = ly * 128;
  const int col0 = lx * 128;

  f32x4 acc[4][4] = {};

  const int c0 = tid, c1 = tid + 256;
  const bf16* Ab0 = A + (size_t)(row0 + (c0 >> 2)) * K + (c0 & 3) * 8;
  const bf16* Ab1 = A + (size_t)(row0 + (c1 >> 2)) * K + (c1 & 3) * 8;
  const bf16* Bb0 = W + (size_t)(col0 + (c0 >> 2)) * K + (c0 & 3) * 8;
  const bf16* Bb1 = W + (size_t)(col0 + (c1 >> 2)) * K + (c1 & 3) * 8;

  auto stage = [&](int kt, int buf) {
    gload16(Ab0 + kt, &lA[buf][c0 * 8]);
    gload16(Ab1 + kt, &lA[buf][c1 * 8]);
    gload16(Bb0 + kt, &lB[buf][c0 * 8]);
    gload16(Bb1 + kt, &lB[buf][c1 * 8]);
  };

  auto comptile = [&](int cur) {
    bf16x8 af[4], bfrag[4];
#pragma unroll
    for (int mi = 0; mi < 4; mi++)
      af[mi] = *(const bf16x8*)&lA[cur][(wr * 64 + mi * 16 + l16) * 32 + quad * 8];
#pragma unroll
    for (int ni = 0; ni < 4; ni++)
      bfrag[ni] = *(const bf16x8*)&lB[cur][(wc * 64 + ni * 16 + l16) * 32 + quad * 8];
#pragma unroll
    for (int mi = 0; mi < 4; mi++)
#pragma unroll
      for (int ni = 0; ni < 4; ni++)
        acc[mi][ni] = __builtin_amdgcn_mfma_f32_16x16x32_bf16(
            af[mi], bfrag[ni], acc[mi][ni], 0, 0, 0);
  };

  // prologue: tiles 0 and 1 issued (8 VMEM ops/wave in flight)
  stage(0, 0);
  stage(32, 1);
  asm volatile("s_waitcnt vmcnt(4)" ::: "memory");   // tile0 done; tile1 in flight
  __builtin_amdgcn_s_barrier();
  asm volatile("" ::: "memory");

#pragma unroll 3
  for (int t = 0; t < 30; ++t) {
    stage((t + 2) * 32, (t + 2) % 3);   // overwrites buffer read in iter t-1
    comptile(t % 3);
    asm volatile("s_waitcnt vmcnt(4)" ::: "memory"); // drain stage(t+1); keep t+2
    __builtin_amdgcn_s_barrier();
    asm volatile("" ::: "memory");
  }
  // t = 30 (no new stage; drain the last tile fully)
  comptile(0);
  asm volatile("s_waitcnt vmcnt(0)" ::: "memory");
  __builtin_amdgcn_s_barrier();
  asm volatile("" ::: "memory");
  // t = 31
  comptile(1);

#pragma unroll
  for (int mi = 0; mi < 4; mi++) {
#pragma unroll
    for (int ni = 0; ni < 4; ni++) {
      const int gcol = col0 + wc * 64 + ni * 16 + l16;
      const float bv = bias[gcol];
#pragma unroll
      for (int r = 0; r < 4; r++) {
        const int grow = row0 + wr * 64 + mi * 16 + quad * 4 + r;
        C[(size_t)grow * 1024 + gcol] = (OutT)(acc[mi][ni][r] + bv);
      }
    }
  }
}

__global__ __launch_bounds__(256) void gemm_qkv_kernel(
    const bf16* xq, const bf16* xk, const bf16* xv,
    const bf16* wq, const bf16* wk, const bf16* wv,
    const float* bq, const float* bk, const float* bv,
    bf16* q, bf16* k, bf16* v)
{
  const bf16 *A, *W; const float* bias; bf16* C;
  if (blockIdx.z == 0)      { A = xq; W = wq; bias = bq; C = q; }
  else if (blockIdx.z == 1) { A = xk; W = wk; bias = bk; C = k; }
  else                      { A = xv; W = wv; bias = bv; C = v; }
  gemm_body<bf16>(A, W, bias, C);
}

__global__ __launch_bounds__(256) void gemm_out_kernel(
    const bf16* A, const bf16* W, const float* bias, float* C)
{
  gemm_body<float>(A, W, bias, C);
}

// ---------------------------------------------------------------------------
// V transpose into per-branch sparse-contiguous layout: vt_b[seg][h][d][kj'].
// kj' is PAIR-PERMUTED within each 64-kpos tile-row: chunk c' = p2*4 + q
// (p2 in {0,1}, q in {0..3}) holds old kpos {p2*32+q*4..+4} ++
// {p2*32+16+q*4..+4}, so one 16B read serves MFMA pair (t=2p2, 2p2+1).
// ---------------------------------------------------------------------------
__global__ __launch_bounds__(256) void vtrans_kernel(
    const bf16* __restrict__ v, bf16* vt0, bf16* vt1, bf16* vt2)
{
  __shared__ __align__(16) bf16 ltile[64 * 72];   // [kj][d], padded
  const int bid = blockIdx.x;
  int sl, dr, rem, shift; bf16* vt;
  if (bid < 1024)      { sl = 1024; dr = 1; rem = bid;        vt = vt0; shift = 4; }
  else if (bid < 1536) { sl = 2048; dr = 2; rem = bid - 1024; vt = vt1; shift = 3; }
  else                 { sl = 4096; dr = 4; rem = bid - 1536; vt = vt2; shift = 2; }
  const int ktile = rem & 15;
  const int h     = (rem >> 4) & 15;
  const int seg   = rem >> 8;
  const int grp   = h >> shift;          // h / (16/dr)
  const int segbase = seg * sl;
  const int tid = threadIdx.x;
  {
    const int i = tid >> 2, dc = tid & 3;
    const size_t p = (size_t)(segbase + (ktile * 64 + i) * dr + grp);
    const bf16* src = v + p * EDIM + h * 64 + dc * 16;
    *(uint4*)&ltile[i * 72 + dc * 16]     = *(const uint4*)(src);
    *(uint4*)&ltile[i * 72 + dc * 16 + 8] = *(const uint4*)(src + 8);
  }
  __syncthreads();
  {
    const int d = tid >> 2, kc = tid & 3;   // kc = t (old 16-kpos group)
    __align__(16) bf16 tmp[16];
#pragma unroll
    for (int j = 0; j < 16; j++) tmp[j] = ltile[(kc * 16 + j) * 72 + d];
    // pair-permuted destination: newpos = p2*32 + q*8 + half*4 + r
    const int p2 = kc >> 1, half = kc & 1;
    bf16* dst = vt + ((size_t)(seg * NH + h) * 64 + d) * GLEN + ktile * 64
                   + p2 * 32 + half * 4;
#pragma unroll
    for (int q = 0; q < 4; q++) {
      bf16x4 piece = { tmp[q * 4 + 0], tmp[q * 4 + 1],
                       tmp[q * 4 + 2], tmp[q * 4 + 3] };
      *(bf16x4*)(dst + q * 8) = piece;
    }
  }
}

// ---------------------------------------------------------------------------
// Flash attention, transposed-S form with XOR-swizzled LDS tiles.
// Block = (branch, seg, h, pair j): q-tiles qtA = 15-j and qtB = j over one
// shared staged K/V stream. Dual-tile fused compute: both tiles consume the
// SAME K/V fragments, softmax chains interleave. l-sum via ones-MFMA.
// ---------------------------------------------------------------------------
__global__ __launch_bounds__(256, 4) void attn_kernel(
    const bf16* __restrict__ qg, const bf16* __restrict__ kg,
    const bf16* vt0, const bf16* vt1, const bf16* vt2,
    bf16* o0, bf16* o1, bf16* o2,
    float* l0, float* l1, float* l2)
{
  __shared__ __align__(16) bf16 lK[2][64 * 64];     // [kj][d], swizzled
  __shared__ __align__(16) bf16 lV[2][64 * 64];     // [d][kj'], swizzled

  // XCD-affinity remap (bijective, 896 = 8*112): hardware assigns block b to
  // XCD b%8; logical id o = (b&7)*112 + (b>>3) gives each XCD a contiguous
  // run of 112 logical blocks = 14 (seg,h) groups -> K/V fits that XCD's L2.
  const int bid0 = blockIdx.x;
  const int o = (bid0 & 7) * 112 + (bid0 >> 3);

  int sl, dr, rem, shift;
  const bf16* vt; bf16* ob; float* lseb;
  if (o < 512)      { sl = 1024; dr = 1; rem = o;       vt = vt0; ob = o0; lseb = l0; shift = 4; }
  else if (o < 768) { sl = 2048; dr = 2; rem = o - 512; vt = vt1; ob = o1; lseb = l1; shift = 3; }
  else              { sl = 4096; dr = 4; rem = o - 768; vt = vt2; ob = o2; lseb = l2; shift = 2; }
  const int j   = rem & 7;
  const int h   = (rem >> 3) & 15;
  const int seg = rem >> 7;
  const int qtA = 15 - j;                // high q-tile (16-j k-iterations)
  const int qtB = j;                     // low q-tile  (j+1 k-iterations); qtB < qtA
  const int grp = h >> shift;
  const int segbase = seg * sl;

  const int tid = threadIdx.x, lane = tid & 63, w = tid >> 6;
  const int quad = lane >> 4, l16 = lane & 15;
  const int rs8 = l16 & 7;               // row-XOR term: (kj&7)==(drow&7)==l16&7

  // Q fragments (B-operand of S^T MFMA): B[k=d=quad*8+j][n=q=l16]
  auto loadq = [&](int qt, bf16x8& a0, bf16x8& a1) {
    const int qi = qt * 64 + w * 16 + l16;
    const size_t p = (size_t)(segbase + qi * dr + grp);
    const bf16* qp = qg + p * EDIM + h * 64 + quad * 8;
    a0 = *(const bf16x8*)(qp);
    a1 = *(const bf16x8*)(qp + 32);
  };
  bf16x8 qaA0, qaA1, qaB0, qaB1;
  loadq(qtA, qaA0, qaA1);
  loadq(qtB, qaB0, qaB1);

  f32x4 OA[4] = {}, OB[4] = {};          // O^T frags: col l16=q, row = d
  f32x4 lsA = {0.f, 0.f, 0.f, 0.f};      // l accumulated by ones-MFMA
  f32x4 lsB = {0.f, 0.f, 0.f, 0.f};
  float mA = -__builtin_inff();          // m in log2 units
  float mB = -__builtin_inff();
  const bf16x4 ONES = { (bf16)1.f, (bf16)1.f, (bf16)1.f, (bf16)1.f };

  const bf16* vbase = vt + (size_t)(seg * NH + h) * 64 * GLEN;
  const int c0 = tid, c1 = tid + 256;
  // staging-source permutation implementing the XOR swizzle:
  // LDS chunk position p (=c0/c1) is row r=p>>3, slot s=p&7; it must receive
  // global chunk c = s ^ (r & 7).
  const int r0 = c0 >> 3, sw0 = ((c0 & 7) ^ (r0 & 7));
  const int r1 = c1 >> 3, sw1 = ((c1 & 7) ^ (r1 & 7));

  // incremental staging pointers (advance one k-tile per stage call)
  const bf16* kp0 = kg + (size_t)(segbase + r0 * dr + grp) * EDIM + h * 64 + sw0 * 8;
  const bf16* kp1 = kg + (size_t)(segbase + r1 * dr + grp) * EDIM + h * 64 + sw1 * 8;
  const bf16* vp0 = vbase + (size_t)r0 * GLEN + sw0 * 8;
  const bf16* vp1 = vbase + (size_t)r1 * GLEN + sw1 * 8;
  const size_t kstep = (size_t)64 * dr * EDIM;

  auto stage = [&](int buf) {
    gload16(kp0, &lK[buf][c0 * 8]);
    gload16(kp1, &lK[buf][c1 * 8]);
    gload16(vp0, &lV[buf][c0 * 8]);
    gload16(vp1, &lV[buf][c1 * 8]);
    kp0 += kstep; kp1 += kstep; vp0 += 64; vp1 += 64;
  };

  const float CS = 0.18033688011112042f;   // (1/sqrt(64)) * log2(e)
  const float NEGINF = -__builtin_inff();
  const int qiA = qtA * 64 + w * 16 + l16;
  const int qiB = qtB * 64 + w * 16 + l16;

  // loop-invariant LDS read bases (K: kj = t*16+l16 -> +t*1024; V: +nf*1024)
  const int kb0 = l16 * 64 + ((quad ^ rs8) * 8);
  const int kb1 = l16 * 64 + (((4 + quad) ^ rs8) * 8);
  const int vb0 = l16 * 64;

  // Fused dual-tile compute. HAS_B: tile B active this k-tile. DIAG_A/B:
  // causal-diagonal masking for that tile (DIAG_A implies !HAS_B).
  auto comp = [&](auto hasB_, auto diagA_, auto diagB_, int kt) {
    constexpr bool HAS_B  = decltype(hasB_)::v;
    constexpr bool DIAG_A = decltype(diagA_)::v;
    constexpr bool DIAG_B = decltype(diagB_)::v;
    const bf16* bK = lK[kt & 1];
    const bf16* bV = lV[kt & 1];

    // --- S^T = K Q^T for both tiles off shared K fragments ---
    f32x4 sA[4], sB[4];
#pragma unroll
    for (int t = 0; t < 4; t++) {
      const bool aA = !DIAG_A || t <= w;
      const bool aB = HAS_B && (!DIAG_B || t <= w);
      if (aA || aB) {
        bf16x8 ka0 = *(const bf16x8*)&bK[kb0 + t * 1024];
        bf16x8 ka1 = *(const bf16x8*)&bK[kb1 + t * 1024];
        if (aA) {
          sA[t] = f32x4{0.f, 0.f, 0.f, 0.f};
          sA[t] = __builtin_amdgcn_mfma_f32_16x16x32_bf16(ka0, qaA0, sA[t], 0, 0, 0);
          sA[t] = __builtin_amdgcn_mfma_f32_16x16x32_bf16(ka1, qaA1, sA[t], 0, 0, 0);
        }
        if (aB) {
          sB[t] = f32x4{0.f, 0.f, 0.f, 0.f};
          sB[t] = __builtin_amdgcn_mfma_f32_16x16x32_bf16(ka0, qaB0, sB[t], 0, 0, 0);
          sB[t] = __builtin_amdgcn_mfma_f32_16x16x32_bf16(ka1, qaB1, sB[t], 0, 0, 0);
        }
      }
    }

    // --- masked raw max, vector partials ---
    f32x4 mvA = {NEGINF, NEGINF, NEGINF, NEGINF};
    f32x4 mvB = {NEGINF, NEGINF, NEGINF, NEGINF};
#pragma unroll
    for (int t = 0; t < 4; t++) {
      if (!DIAG_A || t <= w) {
#pragma unroll
        for (int r = 0; r < 4; r++) {
          float sv = sA[t][r];
          if (DIAG_A) {
            const int kj = kt * 64 + t * 16 + quad * 4 + r;
            if (kj > qiA) sv = NEGINF;
          }
          sA[t][r] = sv;
          mvA[r] = fmaxf(mvA[r], sv);
        }
      }
      if (HAS_B && (!DIAG_B || t <= w)) {
#pragma unroll
        for (int r = 0; r < 4; r++) {
          float sv = sB[t][r];
          if (DIAG_B) {
            const int kj = kt * 64 + t * 16 + quad * 4 + r;
            if (kj > qiB) sv = NEGINF;
          }
          sB[t][r] = sv;
          mvB[r] = fmaxf(mvB[r], sv);
        }
      }
    }
    float mrA = fmaxf(fmaxf(mvA[0], mvA[1]), fmaxf(mvA[2], mvA[3]));
    float mrB = fmaxf(fmaxf(mvB[0], mvB[1]), fmaxf(mvB[2], mvB[3]));
    mrA = fmaxf(mrA, __shfl_xor(mrA, 16, 64));
    mrA = fmaxf(mrA, __shfl_xor(mrA, 32, 64));
    if constexpr (HAS_B) {
      mrB = fmaxf(mrB, __shfl_xor(mrB, 16, 64));
      mrB = fmaxf(mrB, __shfl_xor(mrB, 32, 64));
    }

    // --- defer-rescale (T13), wave-uniform skip ---
    {
      const float mnew = fmaxf(mA, mrA * CS);
      if (!__all(mnew - mA <= 8.0f)) {
        const float alpha = fast_exp2(mA - mnew);   // first tile: exp2(-inf)=0
#pragma unroll
        for (int nf = 0; nf < 4; nf++)
#pragma unroll
          for (int r = 0; r < 4; r++) OA[nf][r] *= alpha;
#pragma unroll
        for (int r = 0; r < 4; r++) lsA[r] *= alpha;
        mA = mnew;
      }
    }
    if constexpr (HAS_B) {
      const float mnew = fmaxf(mB, mrB * CS);
      if (!__all(mnew - mB <= 8.0f)) {
        const float alpha = fast_exp2(mB - mnew);
#pragma unroll
        for (int nf = 0; nf < 4; nf++)
#pragma unroll
          for (int r = 0; r < 4; r++) OB[nf][r] *= alpha;
#pragma unroll
        for (int r = 0; r < 4; r++) lsB[r] *= alpha;
        mB = mnew;
      }
    }

    // --- p = exp2(fma(s_raw, CS, -m)) <= 2^8; bf16 pack ---
    bf16x4 pbA[4], pbB[4];
#pragma unroll
    for (int t = 0; t < 4; t++) {
      if (!DIAG_A || t <= w) {
#pragma unroll
        for (int r = 0; r < 4; r++)
          pbA[t][r] = (bf16)fast_exp2(__builtin_fmaf(sA[t][r], CS, -mA));
      }
      if (HAS_B && (!DIAG_B || t <= w)) {
#pragma unroll
        for (int r = 0; r < 4; r++)
          pbB[t][r] = (bf16)fast_exp2(__builtin_fmaf(sB[t][r], CS, -mB));
      }
    }

    // --- O^T += V^T P^T off shared V fragments (paired b128 reads);
    //     l += ones-MFMA(P^T): full 64-kpos row sum incl. cross-quad ---
#pragma unroll
    for (int p2 = 0; p2 < 2; p2++) {
      const int t0 = 2 * p2, t1 = t0 + 1;
      const bool aA0 = !DIAG_A || t0 <= w;
      const bool aA1 = !DIAG_A || t1 <= w;
      const bool aB0 = HAS_B && (!DIAG_B || t0 <= w);
      const bool aB1 = HAS_B && (!DIAG_B || t1 <= w);
      if (aA0 || aA1 || aB0 || aB1) {
        const int cx = ((p2 * 4 + quad) ^ rs8) * 8;
#pragma unroll
        for (int nf = 0; nf < 4; nf++) {
          bf16x8 va8 = *(const bf16x8*)&bV[vb0 + nf * 1024 + cx];
          bf16x4 vlo = __builtin_shufflevector(va8, va8, 0, 1, 2, 3);
          bf16x4 vhi = __builtin_shufflevector(va8, va8, 4, 5, 6, 7);
          if (aA0) OA[nf] = mfma16x16x16_bf16(vlo, pbA[t0], OA[nf]);
          if (aA1) OA[nf] = mfma16x16x16_bf16(vhi, pbA[t1], OA[nf]);
          if (aB0) OB[nf] = mfma16x16x16_bf16(vlo, pbB[t0], OB[nf]);
          if (aB1) OB[nf] = mfma16x16x16_bf16(vhi, pbB[t1], OB[nf]);
        }
        if (aA0) lsA = mfma16x16x16_bf16(ONES, pbA[t0], lsA);
        if (aA1) lsA = mfma16x16x16_bf16(ONES, pbA[t1], lsA);
        if (aB0) lsB = mfma16x16x16_bf16(ONES, pbB[t0], lsB);
        if (aB1) lsB = mfma16x16x16_bf16(ONES, pbB[t1], lsB);
      }
    }
  };

  stage(0);
  int kt = 0;
  // Phase 1: both tiles, no diagonal (kt < qtB)
  for (; kt < qtB; kt++) {
    __syncthreads();
    stage((kt + 1) & 1);
    comp(Flag<true>{}, Flag<false>{}, Flag<false>{}, kt);
  }
  // kt == qtB: tile A full, tile B diagonal (qtB < qtA always)
  __syncthreads();
  stage((kt + 1) & 1);
  comp(Flag<true>{}, Flag<false>{}, Flag<true>{}, kt);
  kt++;
  // Phase 2: tile A only (qtB < kt < qtA)
  for (; kt < qtA; kt++) {
    __syncthreads();
    stage((kt + 1) & 1);
    comp(Flag<false>{}, Flag<false>{}, Flag<false>{}, kt);
  }
  // kt == qtA: tile A diagonal
  __syncthreads();
  comp(Flag<false>{}, Flag<true>{}, Flag<false>{}, kt);

  // epilogue: lane l16 owns q column; d = nf*16 + quad*4 + r (4 contiguous)
  auto epilogue = [&](const f32x4 (&Oa)[4], float m_r, float l_r, int qt) {
    const int qi = qt * 64 + w * 16 + l16;
    const float linv = 1.0f / l_r;
    const int pdense = segbase + qi * dr + grp;
    bf16* orow = ob + (size_t)pdense * EDIM + h * 64;
#pragma unroll
    for (int nf = 0; nf < 4; nf++) {
      bf16x4 ov;
#pragma unroll
      for (int r = 0; r < 4; r++) ov[r] = (bf16)(Oa[nf][r] * linv);
      *(bf16x4*)(orow + nf * 16 + quad * 4) = ov;
    }
    if (quad == 0)
      lseb[h * L_SEQ + pdense] = m_r * 0.6931471805599453f + __logf(l_r);
  };
  epilogue(OA, mA, lsA[0], qtA);
  epilogue(OB, mB, lsB[0], qtB);
}

// ---------------------------------------------------------------------------
// Merge: softmax over branch lse at each (h,p); coverage computed analytically.
// ---------------------------------------------------------------------------
__global__ __launch_bounds__(256) void merge_kernel(
    const bf16* __restrict__ o0, const bf16* __restrict__ o1, const bf16* __restrict__ o2,
    const float* __restrict__ l0, const float* __restrict__ l1, const float* __restrict__ l2,
    bf16* __restrict__ merged)
{
  const int idx = blockIdx.x * 256 + threadIdx.x;   // over L*H*8
  const int dc = idx & 7;
  const int h  = (idx >> 3) & 15;
  const int p  = idx >> 7;
  const bool c1 = ((p & 1) == (h >> 3));   // branch dr=2 coverage
  const bool c2 = ((p & 3) == (h >> 2));   // branch dr=4 coverage
  const float s0 = l0[h * L_SEQ + p];
  const float s1 = c1 ? l1[h * L_SEQ + p] : -__builtin_inff();
  const float s2 = c2 ? l2[h * L_SEQ + p] : -__builtin_inff();
  const float mx = fmaxf(s0, fmaxf(s1, s2));
  float w0 = __expf(s0 - mx);
  float w1 = c1 ? __expf(s1 - mx) : 0.f;
  float w2 = c2 ? __expf(s2 - mx) : 0.f;
  const float inv = 1.0f / (w0 + w1 + w2);
  w0 *= inv; w1 *= inv; w2 *= inv;

  const size_t off = (size_t)p * EDIM + h * 64 + dc * 8;
  float acc[8];
  bf16x8 a0 = *(const bf16x8*)(o0 + off);
#pragma unroll
  for (int j = 0; j < 8; j++) acc[j] = w0 * (float)a0[j];
  if (c1) {
    bf16x8 a1 = *(const bf16x8*)(o1 + off);
#pragma unroll
    for (int j = 0; j < 8; j++) acc[j] += w1 * (float)a1[j];
  }
  if (c2) {
    bf16x8 a2 = *(const bf16x8*)(o2 + off);
#pragma unroll
    for (int j = 0; j < 8; j++) acc[j] += w2 * (float)a2[j];
  }
  bf16x8 r;
#pragma unroll
  for (int j = 0; j < 8; j++) r[j] = (bf16)acc[j];
  *(bf16x8*)(merged + off) = r;
}

// ---------------------------------------------------------------------------
extern "C" void kernel_launch(void* const* d_in, const int* in_sizes, int n_in,
                              void* d_out, int out_size, void* d_ws, size_t ws_size,
                              hipStream_t stream)
{
  (void)in_sizes; (void)n_in; (void)out_size; (void)ws_size;
  const float* query = (const float*)d_in[0];
  const float* key   = (const float*)d_in[1];
  const float* value = (const float*)d_in[2];
  const float* Wq = (const float*)d_in[3];
  const float* bq = (const float*)d_in[4];
  const float* Wk = (const float*)d_in[5];
  const float* bk = (const float*)d_in[6];
  const float* Wv = (const float*)d_in[7];
  const float* bv = (const float*)d_in[8];
  const float* Wo = (const float*)d_in[9];
  const float* bo = (const float*)d_in[10];

  char* base = (char*)d_ws;
  size_t off = 0;
  auto take = [&](size_t nbytes) -> char* {
    char* p = base + off;
    off += (nbytes + 255) & ~(size_t)255;
    return p;
  };
  const size_t LE2 = (size_t)L_SEQ * EDIM * 2;
  const size_t EE2 = (size_t)EDIM * EDIM * 2;
  bf16* xq  = (bf16*)take(LE2);
  bf16* xk  = (bf16*)take(LE2);
  bf16* xv  = (bf16*)take(LE2);
  bf16* wqb = (bf16*)take(EE2);
  bf16* wkb = (bf16*)take(EE2);
  bf16* wvb = (bf16*)take(EE2);
  bf16* wob = (bf16*)take(EE2);
  bf16* qb  = (bf16*)take(LE2);
  bf16* kb  = (bf16*)take(LE2);
  bf16* vb  = (bf16*)take(LE2);
  bf16* vt0 = (bf16*)take((size_t)4 * NH * HD * GLEN * 2);
  bf16* vt1 = (bf16*)take((size_t)2 * NH * HD * GLEN * 2);
  bf16* vt2 = (bf16*)take((size_t)1 * NH * HD * GLEN * 2);
  float* lse0 = (float*)take((size_t)NH * L_SEQ * 4);
  float* lse1 = (float*)take((size_t)NH * L_SEQ * 4);
  float* lse2 = (float*)take((size_t)NH * L_SEQ * 4);
  bf16* merged = (bf16*)take(LE2);
  // branch outputs alias the converted inputs (dead after gemm_qkv)
  bf16* o0 = xq; bf16* o1 = xk; bf16* o2 = xv;

  dim3 blk(256);
  cvt_kernel<<<dim3(8192), blk, 0, stream>>>(
      query, key, value, Wq, Wk, Wv, Wo, xq, xk, xv, wqb, wkb, wvb, wob);
  gemm_qkv_kernel<<<dim3(8, 32, 3), blk, 0, stream>>>(
      xq, xk, xv, wqb, wkb, wvb, bq, bk, bv, qb, kb, vb);
  vtrans_kernel<<<dim3(1792), blk, 0, stream>>>(vb, vt0, vt1, vt2);
  attn_kernel<<<dim3(896), blk, 0, stream>>>(
      qb, kb, vt0, vt1, vt2, o0, o1, o2, lse0, lse1, lse2);
  merge_kernel<<<dim3(2048), blk, 0, stream>>>(
      o0, o1, o2, lse0, lse1, lse2, merged);
  gemm_out_kernel<<<dim3(8, 32), blk, 0, stream>>>(merged, wob, bo, (float*)d_out);
}

// Round 8
// 217.404 us; speedup vs baseline: 1.1065x; 1.0469x over previous
//
#include <hip/hip_runtime.h>
#include <math.h>

// DilatedAttention on MI355X (gfx950), bf16 MFMA implementation.
// L=4096, E=1024, H=16, D=64. Branches (sl,dr) = (1024,1),(2048,2),(4096,4).
// Every branch reduces to causal attention over g=1024 sparse positions.
//
// Attention in transposed-S form:
//   S^T = K Q^T  (lane l16 = q column)
//   O^T = V^T P^T with 16x16x16 MFMA    -> P^T registers are the B-operand.
// R4: XOR-swizzled LDS tiles via staging-source permutation.
// R5: q-tile PAIR (j, 15-j) per block: exactly 17 tile-computes each.
// R6: fused dual-tile compute (shared K/V fragments, interleaved chains).
// R7: GEMM/attn XCD-affinity remaps; V^T pair-permuted (bank conflicts -> 0).
// R8: attn l-sum via ones-MFMA; setprio removed (measured regression).
// R9 (FAILED): fused fp32->bf16 A-conv on gemm K-loop critical path.
// R10 (NULL) / R11 (REGRESSED): T3-dbuf / T4 counted-vmcnt on the 128² GEMM
// -- 16 MFMA/step can't cover ~200cy L2 latency; 48KB LDS cut occupancy
// 24->16%. GEMM scheduling is plateaued at ~44us for this tile shape; frozen.
// R12: (a) gemm_body reverted to the measured-best 2-barrier 16KB loop.
// (b) vtrans FUSED into gemm_qkv's V epilogue (6 launches -> 5): the V
// C-tile write goes directly into the three per-branch vt layouts (pair-
// permute baked into index math; epilogue-only change, K-loop untouched).
// Motivation: dispatch-sum is ~130us vs ~228 total -- ~95-100us of FIXED
// inter-dispatch cost; launch-count reduction tests that hypothesis.

#define L_SEQ 4096
#define EDIM  1024
#define NH    16
#define HD    64
#define GLEN  1024

typedef __bf16 bf16;
typedef __bf16 bf16x8 __attribute__((ext_vector_type(8)));
typedef __bf16 bf16x4 __attribute__((ext_vector_type(4)));
typedef __bf16 bf16x2 __attribute__((ext_vector_type(2)));
typedef short  s16x4  __attribute__((ext_vector_type(4)));
typedef float  f32x4  __attribute__((ext_vector_type(4)));

template <bool B> struct Flag { static constexpr bool v = B; };

// async global->LDS, 16B per lane. LDS dest semantics: wave-uniform base + lane*16.
__device__ __forceinline__ void gload16(const bf16* g, bf16* l) {
  __builtin_amdgcn_global_load_lds(
      (__attribute__((address_space(1))) void*)(const_cast<bf16*>(g)),
      (__attribute__((address_space(3))) void*)(l),
      16, 0, 0);
}

// v_mfma_f32_16x16x16_bf16 (builtin name only exists in the device pass).
__device__ __forceinline__ f32x4 mfma16x16x16_bf16(bf16x4 a, bf16x4 b, f32x4 c) {
#if defined(__HIP_DEVICE_COMPILE__)
  union { bf16x4 h; s16x4 s; } ua, ub;
  ua.h = a; ub.h = b;
  return __builtin_amdgcn_mfma_f32_16x16x16bf16_1k(ua.s, ub.s, c, 0, 0, 0);
#else
  (void)a; (void)b;
  return c;   // host stub, never executed
#endif
}

__device__ __forceinline__ float fast_exp2(float x) {
#if __has_builtin(__builtin_amdgcn_exp2f)
  return __builtin_amdgcn_exp2f(x);
#else
  return __expf(x * 0.6931471805599453f);
#endif
}

// ---------------------------------------------------------------------------
// fp32 -> bf16 conversion, exact-cover 1D grid (8192 blocks x 256 x 8 elems):
// elems [0,12M): q/k/v (4M=2^22 each); [12M,16M): Wq/Wk/Wv/Wo (1M=2^20 each).
// ---------------------------------------------------------------------------
__global__ __launch_bounds__(256) void cvt_kernel(
    const float* q, const float* k, const float* v,
    const float* wq, const float* wk, const float* wv, const float* wo,
    bf16* oq, bf16* ok, bf16* ov,
    bf16* owq, bf16* owk, bf16* owv, bf16* owo)
{
  const size_t e = ((size_t)blockIdx.x * 256 + threadIdx.x) * 8;
  const float* src; bf16* dst; size_t off;
  if (e < (size_t)12 * 1024 * 1024) {
    const int s = (int)(e >> 22);
    off = e & (((size_t)1 << 22) - 1);
    src = (s == 0) ? q : (s == 1) ? k : v;
    dst = (s == 0) ? oq : (s == 1) ? ok : ov;
  } else {
    const size_t e2 = e - (size_t)12 * 1024 * 1024;
    const int s = (int)(e2 >> 20);
    off = e2 & (((size_t)1 << 20) - 1);
    src = (s == 0) ? wq : (s == 1) ? wk : (s == 2) ? wv : wo;
    dst = (s == 0) ? owq : (s == 1) ? owk : (s == 2) ? owv : owo;
  }
  const float4* s4 = (const float4*)(src + off);
  float4 a = s4[0], b = s4[1];
  bf16x8 o = { (bf16)a.x, (bf16)a.y, (bf16)a.z, (bf16)a.w,
               (bf16)b.x, (bf16)b.y, (bf16)b.z, (bf16)b.w };
  *(bf16x8*)(dst + off) = o;
}

// ---------------------------------------------------------------------------
// GEMM: C[m][n] = sum_k A[m][k] * W[n][k] + bias[n]   (B^T layout)
// M=4096, N=1024, K=1024. 128x128 tile, BK=32, 4 waves (2x2 of 64x64),
// 16x16x32 bf16 MFMA, global_load_lds staging (2-barrier loop -- measured
// plateau for this tile shape; R10/R11 pipelining variants were null/worse).
// Grid MUST be (8, 32[, z]); XCD-affinity: HW XCD = flat%8 = blockIdx.x;
// XCD x owns row-panels [x*4, x*4+4) (A panels hit one XCD L2).
// vfuse: V-instance epilogue writes directly into the 3 per-branch
// vt layouts (vt_b[seg][h][d][kj'] with kj' pair-permuted) instead of C.
// Per thread, rows r=0..3 are 4 consecutive dense positions p (aligned 4):
//   dr=1: 4 consecutive kj  -> one bf16x4 store
//   dr=2: rows {grp1,grp1+2} -> kj,kj+1 -> one bf16x2 store
//   dr=4: row grp2 -> one scalar store
// pair-permute: nw(kj) = (t16>>1)*32 + (j16>>2)*8 + (t16&1)*4 + (j16&3),
// t16 = (kj>>4)&3, j16 = kj&15 (matches the old vtrans layout exactly).
// ---------------------------------------------------------------------------
template <typename OutT>
__device__ __forceinline__ void gemm_body(const bf16* __restrict__ A,
                                          const bf16* __restrict__ W,
                                          const float* __restrict__ bias,
                                          OutT* __restrict__ C,
                                          bf16* __restrict__ vt0,
                                          bf16* __restrict__ vt1,
                                          bf16* __restrict__ vt2,
                                          const bool vfuse)
{
  constexpr int K = 1024;
  __shared__ __align__(16) bf16 lA[128 * 32];
  __shared__ __align__(16) bf16 lB[128 * 32];

  const int tid  = threadIdx.x;
  const int lane = tid & 63;
  const int w    = tid >> 6;
  const int quad = lane >> 4;
  const int l16  = lane & 15;
  const int wr   = w >> 1, wc = w & 1;
  // XCD-affinity remap (bijective over 8x32): ly=x*4+(y>>3), lx=y&7
  const int ly = blockIdx.x * 4 + (blockIdx.y >> 3);
  const int lx = blockIdx.y & 7;
  const int row0 = ly * 128;
  const int col0 = lx * 128;

  f32x4 acc[4][4] = {};

  const int c0 = tid, c1 = tid + 256;
  const bf16* Ab0 = A + (size_t)(row0 + (c0 >> 2)) * K + (c0 & 3) * 8;
  const bf16* Ab1 = A + (size_t)(row0 + (c1 >> 2)) * K + (c1 & 3) * 8;
  const bf16* Bb0 = W + (size_t)(col0 + (c0 >> 2)) * K + (c0 & 3) * 8;
  const bf16* Bb1 = W + (size_t)(col0 + (c1 >> 2)) * K + (c1 & 3) * 8;

  for (int kt = 0; kt < K; kt += 32) {
    __syncthreads();
    gload16(Ab0 + kt, &lA[c0 * 8]);
    gload16(Ab1 + kt, &lA[c1 * 8]);
    gload16(Bb0 + kt, &lB[c0 * 8]);
    gload16(Bb1 + kt, &lB[c1 * 8]);
    __syncthreads();

    bf16x8 af[4], bfrag[4];
#pragma unroll
    for (int mi = 0; mi < 4; mi++)
      af[mi] = *(const bf16x8*)&lA[(wr * 64 + mi * 16 + l16) * 32 + quad * 8];
#pragma unroll
    for (int ni = 0; ni < 4; ni++)
      bfrag[ni] = *(const bf16x8*)&lB[(wc * 64 + ni * 16 + l16) * 32 + quad * 8];
#pragma unroll
    for (int mi = 0; mi < 4; mi++)
#pragma unroll
      for (int ni = 0; ni < 4; ni++)
        acc[mi][ni] = __builtin_amdgcn_mfma_f32_16x16x32_bf16(
            af[mi], bfrag[ni], acc[mi][ni], 0, 0, 0);
  }

  if (!vfuse) {
#pragma unroll
    for (int mi = 0; mi < 4; mi++) {
#pragma unroll
      for (int ni = 0; ni < 4; ni++) {
        const int gcol = col0 + wc * 64 + ni * 16 + l16;
        const float bv = bias[gcol];
#pragma unroll
        for (int r = 0; r < 4; r++) {
          const int grow = row0 + wr * 64 + mi * 16 + quad * 4 + r;
          C[(size_t)grow * 1024 + gcol] = (OutT)(acc[mi][ni][r] + bv);
        }
      }
    }
  } else {
    // V-instance: scatter biased C directly into vt0/vt1/vt2.
    const int h    = 2 * lx + wc;          // this wave's head (cols h*64..h*64+63)
    const int grp1 = h >> 3, grp2 = h >> 2;
#pragma unroll
    for (int mi = 0; mi < 4; mi++) {
      const int p0 = row0 + wr * 64 + mi * 16 + quad * 4;   // aligned 4
      // branch 0 (dr=1, sl=1024): kj = pos0 + r
      const int seg0 = p0 >> 10;
      const int pos0 = p0 & 1023;
      const int nw0  = ((pos0 >> 5) & 1) * 32 + ((pos0 >> 2) & 3) * 8
                     + ((pos0 >> 4) & 1) * 4;                // (pos0&3)==0
      const int kt0  = (pos0 >> 6) * 64;
      // branch 1 (dr=2, sl=2048): kept r in {grp1, grp1+2}; kj = kja, kja+1
      const int seg1 = p0 >> 11;
      const int kja  = (p0 & 2047) >> 1;                     // aligned 2
      const int nw1  = ((kja >> 5) & 1) * 32 + ((kja >> 2) & 3) * 8
                     + ((kja >> 4) & 1) * 4 + (kja & 3);     // even
      const int kt1  = (kja >> 6) * 64;
      // branch 2 (dr=4, sl=4096): kept r = grp2; kj2 = p0>>2
      const int kj2  = p0 >> 2;
      const int nw2  = ((kj2 >> 5) & 1) * 32 + ((kj2 >> 2) & 3) * 8
                     + ((kj2 >> 4) & 1) * 4 + (kj2 & 3);
      const int kt2  = (kj2 >> 6) * 64;
#pragma unroll
      for (int ni = 0; ni < 4; ni++) {
        const int d  = ni * 16 + l16;
        const float bv = bias[col0 + wc * 64 + d];
        const float v0 = acc[mi][ni][0] + bv;
        const float v1 = acc[mi][ni][1] + bv;
        const float v2 = acc[mi][ni][2] + bv;
        const float v3 = acc[mi][ni][3] + bv;
        {
          bf16x4 o = { (bf16)v0, (bf16)v1, (bf16)v2, (bf16)v3 };
          *(bf16x4*)(vt0 + (size_t)((seg0 * 16 + h) * 64 + d) * 1024 + kt0 + nw0) = o;
        }
        {
          const float a = grp1 ? v1 : v0;    // r = grp1
          const float b = grp1 ? v3 : v2;    // r = grp1 + 2
          bf16x2 o = { (bf16)a, (bf16)b };
          *(bf16x2*)(vt1 + (size_t)((seg1 * 16 + h) * 64 + d) * 1024 + kt1 + nw1) = o;
        }
        {
          const float a = (grp2 == 0) ? v0 : (grp2 == 1) ? v1
                         : (grp2 == 2) ? v2 : v3;            // r = grp2
          vt2[(size_t)(h * 64 + d) * 1024 + kt2 + nw2] = (bf16)a;
        }
      }
    }
  }
}

__global__ __launch_bounds__(256) void gemm_qkv_kernel(
    const bf16* xq, const bf16* xk, const bf16* xv,
    const bf16* wq, const bf16* wk, const bf16* wv,
    const float* bq, const float* bk, const float* bv,
    bf16* q, bf16* k,
    bf16* vt0, bf16* vt1, bf16* vt2)
{
  if (blockIdx.z == 0)
    gemm_body<bf16>(xq, wq, bq, q, nullptr, nullptr, nullptr, false);
  else if (blockIdx.z == 1)
    gemm_body<bf16>(xk, wk, bk, k, nullptr, nullptr, nullptr, false);
  else
    gemm_body<bf16>(xv, wv, bv, (bf16*)nullptr, vt0, vt1, vt2, true);
}

__global__ __launch_bounds__(256) void gemm_out_kernel(
    const bf16* A, const bf16* W, const float* bias, float* C)
{
  gemm_body<float>(A, W, bias, C, nullptr, nullptr, nullptr, false);
}

// ---------------------------------------------------------------------------
// Flash attention, transposed-S form with XOR-swizzled LDS tiles.
// Block = (branch, seg, h, pair j): q-tiles qtA = 15-j and qtB = j over one
// shared staged K/V stream. Dual-tile fused compute: both tiles consume the
// SAME K/V fragments, softmax chains interleave. l-sum via ones-MFMA.
// ---------------------------------------------------------------------------
__global__ __launch_bounds__(256, 4) void attn_kernel(
    const bf16* __restrict__ qg, const bf16* __restrict__ kg,
    const bf16* vt0, const bf16* vt1, const bf16* vt2,
    bf16* o0, bf16* o1, bf16* o2,
    float* l0, float* l1, float* l2)
{
  __shared__ __align__(16) bf16 lK[2][64 * 64];     // [kj][d], swizzled
  __shared__ __align__(16) bf16 lV[2][64 * 64];     // [d][kj'], swizzled

  // XCD-affinity remap (bijective, 896 = 8*112): hardware assigns block b to
  // XCD b%8; logical id o = (b&7)*112 + (b>>3) gives each XCD a contiguous
  // run of 112 logical blocks = 14 (seg,h) groups -> K/V fits that XCD's L2.
  const int bid0 = blockIdx.x;
  const int o = (bid0 & 7) * 112 + (bid0 >> 3);

  int sl, dr, rem, shift;
  const bf16* vt; bf16* ob; float* lseb;
  if (o < 512)      { sl = 1024; dr = 1; rem = o;       vt = vt0; ob = o0; lseb = l0; shift = 4; }
  else if (o < 768) { sl = 2048; dr = 2; rem = o - 512; vt = vt1; ob = o1; lseb = l1; shift = 3; }
  else              { sl = 4096; dr = 4; rem = o - 768; vt = vt2; ob = o2; lseb = l2; shift = 2; }
  const int j   = rem & 7;
  const int h   = (rem >> 3) & 15;
  const int seg = rem >> 7;
  const int qtA = 15 - j;                // high q-tile (16-j k-iterations)
  const int qtB = j;                     // low q-tile  (j+1 k-iterations); qtB < qtA
  const int grp = h >> shift;
  const int segbase = seg * sl;

  const int tid = threadIdx.x, lane = tid & 63, w = tid >> 6;
  const int quad = lane >> 4, l16 = lane & 15;
  const int rs8 = l16 & 7;               // row-XOR term: (kj&7)==(drow&7)==l16&7

  // Q fragments (B-operand of S^T MFMA): B[k=d=quad*8+j][n=q=l16]
  auto loadq = [&](int qt, bf16x8& a0, bf16x8& a1) {
    const int qi = qt * 64 + w * 16 + l16;
    const size_t p = (size_t)(segbase + qi * dr + grp);
    const bf16* qp = qg + p * EDIM + h * 64 + quad * 8;
    a0 = *(const bf16x8*)(qp);
    a1 = *(const bf16x8*)(qp + 32);
  };
  bf16x8 qaA0, qaA1, qaB0, qaB1;
  loadq(qtA, qaA0, qaA1);
  loadq(qtB, qaB0, qaB1);

  f32x4 OA[4] = {}, OB[4] = {};          // O^T frags: col l16=q, row = d
  f32x4 lsA = {0.f, 0.f, 0.f, 0.f};      // l accumulated by ones-MFMA
  f32x4 lsB = {0.f, 0.f, 0.f, 0.f};
  float mA = -__builtin_inff();          // m in log2 units
  float mB = -__builtin_inff();
  const bf16x4 ONES = { (bf16)1.f, (bf16)1.f, (bf16)1.f, (bf16)1.f };

  const bf16* vbase = vt + (size_t)(seg * NH + h) * 64 * GLEN;
  const int c0 = tid, c1 = tid + 256;
  // staging-source permutation implementing the XOR swizzle:
  // LDS chunk position p (=c0/c1) is row r=p>>3, slot s=p&7; it must receive
  // global chunk c = s ^ (r & 7).
  const int r0 = c0 >> 3, sw0 = ((c0 & 7) ^ (r0 & 7));
  const int r1 = c1 >> 3, sw1 = ((c1 & 7) ^ (r1 & 7));

  // incremental staging pointers (advance one k-tile per stage call)
  const bf16* kp0 = kg + (size_t)(segbase + r0 * dr + grp) * EDIM + h * 64 + sw0 * 8;
  const bf16* kp1 = kg + (size_t)(segbase + r1 * dr + grp) * EDIM + h * 64 + sw1 * 8;
  const bf16* vp0 = vbase + (size_t)r0 * GLEN + sw0 * 8;
  const bf16* vp1 = vbase + (size_t)r1 * GLEN + sw1 * 8;
  const size_t kstep = (size_t)64 * dr * EDIM;

  auto stage = [&](int buf) {
    gload16(kp0, &lK[buf][c0 * 8]);
    gload16(kp1, &lK[buf][c1 * 8]);
    gload16(vp0, &lV[buf][c0 * 8]);
    gload16(vp1, &lV[buf][c1 * 8]);
    kp0 += kstep; kp1 += kstep; vp0 += 64; vp1 += 64;
  };

  const float CS = 0.18033688011112042f;   // (1/sqrt(64)) * log2(e)
  const float NEGINF = -__builtin_inff();
  const int qiA = qtA * 64 + w * 16 + l16;
  const int qiB = qtB * 64 + w * 16 + l16;

  // loop-invariant LDS read bases (K: kj = t*16+l16 -> +t*1024; V: +nf*1024)
  const int kb0 = l16 * 64 + ((quad ^ rs8) * 8);
  const int kb1 = l16 * 64 + (((4 + quad) ^ rs8) * 8);
  const int vb0 = l16 * 64;

  // Fused dual-tile compute. HAS_B: tile B active this k-tile. DIAG_A/B:
  // causal-diagonal masking for that tile (DIAG_A implies !HAS_B).
  auto comp = [&](auto hasB_, auto diagA_, auto diagB_, int kt) {
    constexpr bool HAS_B  = decltype(hasB_)::v;
    constexpr bool DIAG_A = decltype(diagA_)::v;
    constexpr bool DIAG_B = decltype(diagB_)::v;
    const bf16* bK = lK[kt & 1];
    const bf16* bV = lV[kt & 1];

    // --- S^T = K Q^T for both tiles off shared K fragments ---
    f32x4 sA[4], sB[4];
#pragma unroll
    for (int t = 0; t < 4; t++) {
      const bool aA = !DIAG_A || t <= w;
      const bool aB = HAS_B && (!DIAG_B || t <= w);
      if (aA || aB) {
        bf16x8 ka0 = *(const bf16x8*)&bK[kb0 + t * 1024];
        bf16x8 ka1 = *(const bf16x8*)&bK[kb1 + t * 1024];
        if (aA) {
          sA[t] = f32x4{0.f, 0.f, 0.f, 0.f};
          sA[t] = __builtin_amdgcn_mfma_f32_16x16x32_bf16(ka0, qaA0, sA[t], 0, 0, 0);
          sA[t] = __builtin_amdgcn_mfma_f32_16x16x32_bf16(ka1, qaA1, sA[t], 0, 0, 0);
        }
        if (aB) {
          sB[t] = f32x4{0.f, 0.f, 0.f, 0.f};
          sB[t] = __builtin_amdgcn_mfma_f32_16x16x32_bf16(ka0, qaB0, sB[t], 0, 0, 0);
          sB[t] = __builtin_amdgcn_mfma_f32_16x16x32_bf16(ka1, qaB1, sB[t], 0, 0, 0);
        }
      }
    }

    // --- masked raw max, vector partials ---
    f32x4 mvA = {NEGINF, NEGINF, NEGINF, NEGINF};
    f32x4 mvB = {NEGINF, NEGINF, NEGINF, NEGINF};
#pragma unroll
    for (int t = 0; t < 4; t++) {
      if (!DIAG_A || t <= w) {
#pragma unroll
        for (int r = 0; r < 4; r++) {
          float sv = sA[t][r];
          if (DIAG_A) {
            const int kj = kt * 64 + t * 16 + quad * 4 + r;
            if (kj > qiA) sv = NEGINF;
          }
          sA[t][r] = sv;
          mvA[r] = fmaxf(mvA[r], sv);
        }
      }
      if (HAS_B && (!DIAG_B || t <= w)) {
#pragma unroll
        for (int r = 0; r < 4; r++) {
          float sv = sB[t][r];
          if (DIAG_B) {
            const int kj = kt * 64 + t * 16 + quad * 4 + r;
            if (kj > qiB) sv = NEGINF;
          }
          sB[t][r] = sv;
          mvB[r] = fmaxf(mvB[r], sv);
        }
      }
    }
    float mrA = fmaxf(fmaxf(mvA[0], mvA[1]), fmaxf(mvA[2], mvA[3]));
    float mrB = fmaxf(fmaxf(mvB[0], mvB[1]), fmaxf(mvB[2], mvB[3]));
    mrA = fmaxf(mrA, __shfl_xor(mrA, 16, 64));
    mrA = fmaxf(mrA, __shfl_xor(mrA, 32, 64));
    if constexpr (HAS_B) {
      mrB = fmaxf(mrB, __shfl_xor(mrB, 16, 64));
      mrB = fmaxf(mrB, __shfl_xor(mrB, 32, 64));
    }

    // --- defer-rescale (T13), wave-uniform skip ---
    {
      const float mnew = fmaxf(mA, mrA * CS);
      if (!__all(mnew - mA <= 8.0f)) {
        const float alpha = fast_exp2(mA - mnew);   // first tile: exp2(-inf)=0
#pragma unroll
        for (int nf = 0; nf < 4; nf++)
#pragma unroll
          for (int r = 0; r < 4; r++) OA[nf][r] *= alpha;
#pragma unroll
        for (int r = 0; r < 4; r++) lsA[r] *= alpha;
        mA = mnew;
      }
    }
    if constexpr (HAS_B) {
      const float mnew = fmaxf(mB, mrB * CS);
      if (!__all(mnew - mB <= 8.0f)) {
        const float alpha = fast_exp2(mB - mnew);
#pragma unroll
        for (int nf = 0; nf < 4; nf++)
#pragma unroll
          for (int r = 0; r < 4; r++) OB[nf][r] *= alpha;
#pragma unroll
        for (int r = 0; r < 4; r++) lsB[r] *= alpha;
        mB = mnew;
      }
    }

    // --- p = exp2(fma(s_raw, CS, -m)) <= 2^8; bf16 pack ---
    bf16x4 pbA[4], pbB[4];
#pragma unroll
    for (int t = 0; t < 4; t++) {
      if (!DIAG_A || t <= w) {
#pragma unroll
        for (int r = 0; r < 4; r++)
          pbA[t][r] = (bf16)fast_exp2(__builtin_fmaf(sA[t][r], CS, -mA));
      }
      if (HAS_B && (!DIAG_B || t <= w)) {
#pragma unroll
        for (int r = 0; r < 4; r++)
          pbB[t][r] = (bf16)fast_exp2(__builtin_fmaf(sB[t][r], CS, -mB));
      }
    }

    // --- O^T += V^T P^T off shared V fragments (paired b128 reads);
    //     l += ones-MFMA(P^T): full 64-kpos row sum incl. cross-quad ---
#pragma unroll
    for (int p2 = 0; p2 < 2; p2++) {
      const int t0 = 2 * p2, t1 = t0 + 1;
      const bool aA0 = !DIAG_A || t0 <= w;
      const bool aA1 = !DIAG_A || t1 <= w;
      const bool aB0 = HAS_B && (!DIAG_B || t0 <= w);
      const bool aB1 = HAS_B && (!DIAG_B || t1 <= w);
      if (aA0 || aA1 || aB0 || aB1) {
        const int cx = ((p2 * 4 + quad) ^ rs8) * 8;
#pragma unroll
        for (int nf = 0; nf < 4; nf++) {
          bf16x8 va8 = *(const bf16x8*)&bV[vb0 + nf * 1024 + cx];
          bf16x4 vlo = __builtin_shufflevector(va8, va8, 0, 1, 2, 3);
          bf16x4 vhi = __builtin_shufflevector(va8, va8, 4, 5, 6, 7);
          if (aA0) OA[nf] = mfma16x16x16_bf16(vlo, pbA[t0], OA[nf]);
          if (aA1) OA[nf] = mfma16x16x16_bf16(vhi, pbA[t1], OA[nf]);
          if (aB0) OB[nf] = mfma16x16x16_bf16(vlo, pbB[t0], OB[nf]);
          if (aB1) OB[nf] = mfma16x16x16_bf16(vhi, pbB[t1], OB[nf]);
        }
        if (aA0) lsA = mfma16x16x16_bf16(ONES, pbA[t0], lsA);
        if (aA1) lsA = mfma16x16x16_bf16(ONES, pbA[t1], lsA);
        if (aB0) lsB = mfma16x16x16_bf16(ONES, pbB[t0], lsB);
        if (aB1) lsB = mfma16x16x16_bf16(ONES, pbB[t1], lsB);
      }
    }
  };

  stage(0);
  int kt = 0;
  // Phase 1: both tiles, no diagonal (kt < qtB)
  for (; kt < qtB; kt++) {
    __syncthreads();
    stage((kt + 1) & 1);
    comp(Flag<true>{}, Flag<false>{}, Flag<false>{}, kt);
  }
  // kt == qtB: tile A full, tile B diagonal (qtB < qtA always)
  __syncthreads();
  stage((kt + 1) & 1);
  comp(Flag<true>{}, Flag<false>{}, Flag<true>{}, kt);
  kt++;
  // Phase 2: tile A only (qtB < kt < qtA)
  for (; kt < qtA; kt++) {
    __syncthreads();
    stage((kt + 1) & 1);
    comp(Flag<false>{}, Flag<false>{}, Flag<false>{}, kt);
  }
  // kt == qtA: tile A diagonal
  __syncthreads();
  comp(Flag<false>{}, Flag<true>{}, Flag<false>{}, kt);

  // epilogue: lane l16 owns q column; d = nf*16 + quad*4 + r (4 contiguous)
  auto epilogue = [&](const f32x4 (&Oa)[4], float m_r, float l_r, int qt) {
    const int qi = qt * 64 + w * 16 + l16;
    const float linv = 1.0f / l_r;
    const int pdense = segbase + qi * dr + grp;
    bf16* orow = ob + (size_t)pdense * EDIM + h * 64;
#pragma unroll
    for (int nf = 0; nf < 4; nf++) {
      bf16x4 ov;
#pragma unroll
      for (int r = 0; r < 4; r++) ov[r] = (bf16)(Oa[nf][r] * linv);
      *(bf16x4*)(orow + nf * 16 + quad * 4) = ov;
    }
    if (quad == 0)
      lseb[h * L_SEQ + pdense] = m_r * 0.6931471805599453f + __logf(l_r);
  };
  epilogue(OA, mA, lsA[0], qtA);
  epilogue(OB, mB, lsB[0], qtB);
}

// ---------------------------------------------------------------------------
// Merge: softmax over branch lse at each (h,p); coverage computed analytically.
// ---------------------------------------------------------------------------
__global__ __launch_bounds__(256) void merge_kernel(
    const bf16* __restrict__ o0, const bf16* __restrict__ o1, const bf16* __restrict__ o2,
    const float* __restrict__ l0, const float* __restrict__ l1, const float* __restrict__ l2,
    bf16* __restrict__ merged)
{
  const int idx = blockIdx.x * 256 + threadIdx.x;   // over L*H*8
  const int dc = idx & 7;
  const int h  = (idx >> 3) & 15;
  const int p  = idx >> 7;
  const bool c1 = ((p & 1) == (h >> 3));   // branch dr=2 coverage
  const bool c2 = ((p & 3) == (h >> 2));   // branch dr=4 coverage
  const float s0 = l0[h * L_SEQ + p];
  const float s1 = c1 ? l1[h * L_SEQ + p] : -__builtin_inff();
  const float s2 = c2 ? l2[h * L_SEQ + p] : -__builtin_inff();
  const float mx = fmaxf(s0, fmaxf(s1, s2));
  float w0 = __expf(s0 - mx);
  float w1 = c1 ? __expf(s1 - mx) : 0.f;
  float w2 = c2 ? __expf(s2 - mx) : 0.f;
  const float inv = 1.0f / (w0 + w1 + w2);
  w0 *= inv; w1 *= inv; w2 *= inv;

  const size_t off = (size_t)p * EDIM + h * 64 + dc * 8;
  float acc[8];
  bf16x8 a0 = *(const bf16x8*)(o0 + off);
#pragma unroll
  for (int j = 0; j < 8; j++) acc[j] = w0 * (float)a0[j];
  if (c1) {
    bf16x8 a1 = *(const bf16x8*)(o1 + off);
#pragma unroll
    for (int j = 0; j < 8; j++) acc[j] += w1 * (float)a1[j];
  }
  if (c2) {
    bf16x8 a2 = *(const bf16x8*)(o2 + off);
#pragma unroll
    for (int j = 0; j < 8; j++) acc[j] += w2 * (float)a2[j];
  }
  bf16x8 r;
#pragma unroll
  for (int j = 0; j < 8; j++) r[j] = (bf16)acc[j];
  *(bf16x8*)(merged + off) = r;
}

// ---------------------------------------------------------------------------
extern "C" void kernel_launch(void* const* d_in, const int* in_sizes, int n_in,
                              void* d_out, int out_size, void* d_ws, size_t ws_size,
                              hipStream_t stream)
{
  (void)in_sizes; (void)n_in; (void)out_size; (void)ws_size;
  const float* query = (const float*)d_in[0];
  const float* key   = (const float*)d_in[1];
  const float* value = (const float*)d_in[2];
  const float* Wq = (const float*)d_in[3];
  const float* bq = (const float*)d_in[4];
  const float* Wk = (const float*)d_in[5];
  const float* bk = (const float*)d_in[6];
  const float* Wv = (const float*)d_in[7];
  const float* bv = (const float*)d_in[8];
  const float* Wo = (const float*)d_in[9];
  const float* bo = (const float*)d_in[10];

  char* base = (char*)d_ws;
  size_t off = 0;
  auto take = [&](size_t nbytes) -> char* {
    char* p = base + off;
    off += (nbytes + 255) & ~(size_t)255;
    return p;
  };
  const size_t LE2 = (size_t)L_SEQ * EDIM * 2;
  const size_t EE2 = (size_t)EDIM * EDIM * 2;
  bf16* xq  = (bf16*)take(LE2);
  bf16* xk  = (bf16*)take(LE2);
  bf16* xv  = (bf16*)take(LE2);
  bf16* wqb = (bf16*)take(EE2);
  bf16* wkb = (bf16*)take(EE2);
  bf16* wvb = (bf16*)take(EE2);
  bf16* wob = (bf16*)take(EE2);
  bf16* qb  = (bf16*)take(LE2);
  bf16* kb  = (bf16*)take(LE2);
  bf16* vt0 = (bf16*)take((size_t)4 * NH * HD * GLEN * 2);
  bf16* vt1 = (bf16*)take((size_t)2 * NH * HD * GLEN * 2);
  bf16* vt2 = (bf16*)take((size_t)1 * NH * HD * GLEN * 2);
  float* lse0 = (float*)take((size_t)NH * L_SEQ * 4);
  float* lse1 = (float*)take((size_t)NH * L_SEQ * 4);
  float* lse2 = (float*)take((size_t)NH * L_SEQ * 4);
  bf16* merged = (bf16*)take(LE2);
  // branch outputs alias the converted inputs (dead after gemm_qkv)
  bf16* o0 = xq; bf16* o1 = xk; bf16* o2 = xv;

  dim3 blk(256);
  cvt_kernel<<<dim3(8192), blk, 0, stream>>>(
      query, key, value, Wq, Wk, Wv, Wo, xq, xk, xv, wqb, wkb, wvb, wob);
  gemm_qkv_kernel<<<dim3(8, 32, 3), blk, 0, stream>>>(
      xq, xk, xv, wqb, wkb, wvb, bq, bk, bv, qb, kb, vt0, vt1, vt2);
  attn_kernel<<<dim3(896), blk, 0, stream>>>(
      qb, kb, vt0, vt1, vt2, o0, o1, o2, lse0, lse1, lse2);
  merge_kernel<<<dim3(2048), blk, 0, stream>>>(
      o0, o1, o2, lse0, lse1, lse2, merged);
  gemm_out_kernel<<<dim3(8, 32), blk, 0, stream>>>(merged, wob, bo, (float*)d_out);
}